// Round 7
// baseline (671.069 us; speedup 1.0000x reference)
//
#include <hip/hip_runtime.h>
#include <math.h>

#define NN 25000
#define EE 400000
#define FF 128
#define DD 16
#define HH 64
#define HIDC 128
#define OUTC 32
#define GG 64

typedef __attribute__((ext_vector_type(8))) short short8;
typedef __attribute__((ext_vector_type(4))) float f32x4;

union S8 { short8 v; unsigned short u[8]; };

__device__ __forceinline__ float silu_f(float v) {
    return v / (1.f + __expf(-v));
}

__device__ __forceinline__ unsigned short f2bf_rne(float f) {
  unsigned u = __float_as_uint(f);
  unsigned r = u + 0x7fffu + ((u >> 16) & 1u);
  return (unsigned short)(r >> 16);
}
__device__ __forceinline__ float bfbits2f(unsigned short b) {
  return __uint_as_float(((unsigned)b) << 16);
}

// ---------------- Sort: counting sort of edges by dst ----------------
__global__ __launch_bounds__(256) void k_hist(
    const int* __restrict__ ei, int* __restrict__ cnt) {
  const int t = blockIdx.x * 256 + threadIdx.x;
  if (t < EE) atomicAdd(&cnt[ei[EE + t]], 1);
}

__global__ __launch_bounds__(1024) void k_scan(
    const int* __restrict__ cnt, int* __restrict__ row_ptr, int* __restrict__ next) {
  __shared__ int s[1024];
  const int t = threadIdx.x;
  const int base = t * 25;
  int loc[25];
  int sum = 0;
#pragma unroll
  for (int i = 0; i < 25; ++i) {
    const int n = base + i;
    loc[i] = (n < NN) ? cnt[n] : 0;
    sum += loc[i];
  }
  s[t] = sum;
  __syncthreads();
  for (int off = 1; off < 1024; off <<= 1) {
    const int v = (t >= off) ? s[t - off] : 0;
    __syncthreads();
    s[t] += v;
    __syncthreads();
  }
  int run = s[t] - sum;
#pragma unroll
  for (int i = 0; i < 25; ++i) {
    const int n = base + i;
    if (n < NN) {
      row_ptr[n] = run;
      next[n] = run;
      run += loc[i];
    }
  }
  if (t == 0) row_ptr[NN] = EE;
}

// scatter edges into dst-sorted order; also pre-gather eattr rows into sorted order
__global__ __launch_bounds__(256) void k_scatter(
    const int* __restrict__ ei, const float* __restrict__ eattr, int* __restrict__ next,
    int* __restrict__ sdst, int* __restrict__ ssrc, float* __restrict__ seattr) {
  const int t = blockIdx.x * 256 + threadIdx.x;
  if (t < EE) {
    const int d = ei[EE + t];
    const int slot = atomicAdd(&next[d], 1);
    sdst[slot] = d;
    ssrc[slot] = ei[t];
    const f32x4* s4 = (const f32x4*)&eattr[(size_t)t * DD];
    f32x4* d4 = (f32x4*)&seattr[(size_t)slot * DD];
    d4[0] = s4[0]; d4[1] = s4[1]; d4[2] = s4[2]; d4[3] = s4[3];
  }
}

// ---------------- K1: P1 = X @ W[0:128,:], P2 = X @ W[128:256,:] ----------------
__global__ __launch_bounds__(256) void k_precompute(
    const float* __restrict__ X, const float* __restrict__ W,
    float* __restrict__ P1, float* __restrict__ P2) {
  __shared__ __align__(16) float xT[4][128 * 12];
  const int w = threadIdx.x >> 6, lane = threadIdx.x & 63;
  float* xt = xT[w];
  const int nb = (blockIdx.x * 4 + w) * 8;
#pragma unroll
  for (int e = 0; e < 8; ++e) {
    const int n = nb + e;
    const bool v = n < NN;
    xt[lane * 12 + e]        = v ? X[n * FF + lane] : 0.f;
    xt[(lane + 64) * 12 + e] = v ? X[n * FF + 64 + lane] : 0.f;
  }
  __syncthreads();
  float a1[8], a2[8];
#pragma unroll
  for (int e = 0; e < 8; ++e) { a1[e] = 0.f; a2[e] = 0.f; }
#pragma unroll 4
  for (int k = 0; k < 128; ++k) {
    const float wa = W[k * 64 + lane];
    const float wb = W[(128 + k) * 64 + lane];
    float xk[8];
    *(f32x4*)&xk[0] = *(const f32x4*)&xt[k * 12];
    *(f32x4*)&xk[4] = *(const f32x4*)&xt[k * 12 + 4];
#pragma unroll
    for (int e = 0; e < 8; ++e) {
      a1[e] = fmaf(xk[e], wa, a1[e]);
      a2[e] = fmaf(xk[e], wb, a2[e]);
    }
  }
#pragma unroll
  for (int e = 0; e < 8; ++e) {
    const int n = nb + e;
    if (n < NN) {
      P1[n * 64 + lane] = a1[e];
      P2[n * 64 + lane] = a2[e];
    }
  }
}

// ---------------- K2: per-edge MLP via MFMA, dst-sorted, XCD-swizzled ----------
// 1250 blocks x 320 edges, all co-resident at 6 blocks/CU. Swizzle: contiguous
// dst stripes per XCD -> P1/e_agg stay in one XCD's L2. seattr read sequential.
template <bool COORD>
__global__ __launch_bounds__(256, 6) void k_edge(
    const float* __restrict__ P1, const float* __restrict__ P2,
    const float* __restrict__ pos, const float* __restrict__ seattr,
    const int* __restrict__ sdst, const int* __restrict__ ssrc,
    const float* __restrict__ mlp_w,
    const float* __restrict__ edge_w, const float* __restrict__ edge_b,
    const float* __restrict__ coord_w, const float* __restrict__ coord_b,
    float* __restrict__ e_agg, float* __restrict__ cu) {
  __shared__ int s_src[320], s_dst[320];
  __shared__ __align__(16) float s_hs[4][16 * 76];
  __shared__ float s_diff[4][48];
  __shared__ float s_rad[4][16];
  __shared__ float s_red[4][16];
  const int tid = threadIdx.x, w = tid >> 6, lane = tid & 63;
  const int q = lane >> 4, m = lane & 15;
  // XCD swizzle: physical block b -> XCD b%8; give each XCD a contiguous stripe
  const int b = blockIdx.x;
  const int lb = (b < 1248) ? ((b & 7) * 156 + (b >> 3)) : b;
  const int base = lb * 320;
  for (int t = tid; t < 320; t += 256) {
    s_src[t] = ssrc[base + t];
    s_dst[t] = sdst[base + t];
  }
  __syncthreads();

  S8 wB[2][4];
#pragma unroll
  for (int kc = 0; kc < 2; ++kc)
#pragma unroll
    for (int nc = 0; nc < 4; ++nc)
#pragma unroll
      for (int j = 0; j < 8; ++j)
        wB[kc][nc].u[j] = f2bf_rne(edge_w[(kc * 32 + q * 8 + j) * 64 + nc * 16 + m]);
  S8 w3B[4];
#pragma unroll
  for (int nc = 0; nc < 4; ++nc)
#pragma unroll
    for (int j = 0; j < 8; ++j)
      w3B[nc].u[j] = (lane < 32) ? f2bf_rne(mlp_w[256 * 64 + (q * 8 + j) * 64 + nc * 16 + m])
                                 : (unsigned short)0;
  float w4r[4], cwr[4], ebr[4];
#pragma unroll
  for (int nc = 0; nc < 4; ++nc) {
    w4r[nc] = mlp_w[272 * 64 + nc * 16 + m];
    ebr[nc] = edge_b[nc * 16 + m];
    cwr[nc] = COORD ? coord_w[nc * 16 + m] : 0.f;
  }
  const float cb = COORD ? coord_b[0] : 0.f;

  const int wb = w * 80;
  const int pe = (lane < 48) ? (lane / 3) : 0;
  const int pc = lane - (lane / 3) * 3;

  int cur_dst = -1;
  float accum = 0.f;

  for (int g = 0; g < 5; ++g) {
    const int gb = wb + g * 16;
    const int dm = s_dst[gb + m];
    const int sm = s_src[gb + m];
    f32x4 p1a[2], p1b[2], p2a[2], p2b[2];
#pragma unroll
    for (int kc = 0; kc < 2; ++kc) {
      const float* pp1 = P1 + (size_t)dm * 64 + kc * 32 + q * 8;
      const float* pp2 = P2 + (size_t)sm * 64 + kc * 32 + q * 8;
      p1a[kc] = *(const f32x4*)pp1;
      p1b[kc] = *(const f32x4*)(pp1 + 4);
      p2a[kc] = *(const f32x4*)pp2;
      p2b[kc] = *(const f32x4*)(pp2 + 4);
    }
    if (lane < 48) {
      const int de = s_dst[gb + pe], se = s_src[gb + pe];
      s_diff[w][lane] = pos[de * 3 + pc] - pos[se * 3 + pc];
    }
    // sorted eattr: sequential A-fragment read
    float ea[8] = {0.f, 0.f, 0.f, 0.f, 0.f, 0.f, 0.f, 0.f};
    if (lane < 32) {
      const float* ep = &seattr[(size_t)(base + gb + m) * DD + q * 8];
      *(f32x4*)&ea[0] = *(const f32x4*)ep;
      *(f32x4*)&ea[4] = *(const f32x4*)(ep + 4);
    }
    S8 eaA;
#pragma unroll
    for (int j = 0; j < 8; ++j) eaA.u[j] = f2bf_rne(ea[j]);
    if (lane < 16) {
      const float d0 = s_diff[w][lane * 3 + 0];
      const float d1 = s_diff[w][lane * 3 + 1];
      const float d2 = s_diff[w][lane * 3 + 2];
      s_rad[w][lane] = fmaf(d0, d0, fmaf(d1, d1, d2 * d2));
    }
    float radr[4];
#pragma unroll
    for (int r = 0; r < 4; ++r) radr[r] = s_rad[w][q * 4 + r];
    f32x4 c3[4];
#pragma unroll
    for (int nc = 0; nc < 4; ++nc) {
      f32x4 z = {0.f, 0.f, 0.f, 0.f};
      c3[nc] = __builtin_amdgcn_mfma_f32_16x16x32_bf16(eaA.v, w3B[nc].v, z, 0, 0, 0);
    }
#pragma unroll
    for (int nc = 0; nc < 4; ++nc)
#pragma unroll
      for (int r = 0; r < 4; ++r)
        s_hs[w][(q * 4 + r) * 76 + nc * 16 + m] = fmaf(radr[r], w4r[nc], c3[nc][r]);
    S8 ahi[2], alo[2];
#pragma unroll
    for (int kc = 0; kc < 2; ++kc) {
      const float* hp = &s_hs[w][m * 76 + kc * 32 + q * 8];
      f32x4 h0 = *(const f32x4*)hp;
      f32x4 h1 = *(const f32x4*)(hp + 4);
      h0 = h0 + p1a[kc] + p2a[kc];
      h1 = h1 + p1b[kc] + p2b[kc];
      float hv[8];
      *(f32x4*)&hv[0] = h0;
      *(f32x4*)&hv[4] = h1;
#pragma unroll
      for (int j = 0; j < 8; ++j) {
        const float h = silu_f(hv[j]);
        const unsigned short hb = (unsigned short)(__float_as_uint(h) >> 16);
        ahi[kc].u[j] = hb;
        alo[kc].u[j] = f2bf_rne(h - bfbits2f(hb));
      }
    }
    f32x4 o[4];
#pragma unroll
    for (int nc = 0; nc < 4; ++nc) {
      f32x4 bi = {ebr[nc], ebr[nc], ebr[nc], ebr[nc]};
      o[nc] = bi;
    }
#pragma unroll
    for (int kc = 0; kc < 2; ++kc)
#pragma unroll
      for (int nc = 0; nc < 4; ++nc) {
        o[nc] = __builtin_amdgcn_mfma_f32_16x16x32_bf16(ahi[kc].v, wB[kc][nc].v, o[nc], 0, 0, 0);
        o[nc] = __builtin_amdgcn_mfma_f32_16x16x32_bf16(alo[kc].v, wB[kc][nc].v, o[nc], 0, 0, 0);
      }
#pragma unroll
    for (int nc = 0; nc < 4; ++nc)
#pragma unroll
      for (int r = 0; r < 4; ++r) o[nc][r] = silu_f(o[nc][r]);
    if (COORD) {
#pragma unroll
      for (int r = 0; r < 4; ++r) {
        float v = o[0][r] * cwr[0] + o[1][r] * cwr[1] + o[2][r] * cwr[2] + o[3][r] * cwr[3];
        v += __shfl_xor(v, 1, 64);
        v += __shfl_xor(v, 2, 64);
        v += __shfl_xor(v, 4, 64);
        v += __shfl_xor(v, 8, 64);
        if (m == 0) s_red[w][q * 4 + r] = v;
      }
    }
#pragma unroll
    for (int nc = 0; nc < 4; ++nc)
#pragma unroll
      for (int r = 0; r < 4; ++r)
        s_hs[w][(q * 4 + r) * 76 + nc * 16 + m] = o[nc][r];
    for (int e = 0; e < 16; ++e) {
      const int dv = s_dst[gb + e];
      const float v = s_hs[w][e * 76 + lane];
      if (dv == cur_dst) {
        accum += v;
      } else {
        if (cur_dst >= 0) atomicAdd(&e_agg[(size_t)cur_dst * 64 + lane], accum);
        cur_dst = dv;
        accum = v;
      }
    }
    if (COORD) {
      if (lane < 48) {
        const float s = silu_f(s_red[w][pe] + cb);
        atomicAdd(&cu[(size_t)s_dst[gb + pe] * 3 + pc], s_diff[w][lane] * s);
      }
    }
  }
  if (cur_dst >= 0) atomicAdd(&e_agg[(size_t)cur_dst * 64 + lane], accum);
}

// ------- K3a: layer-0 node MLP + pos update + e_agg rezero + layer-1 precompute -
__global__ __launch_bounds__(256) void k_node_l0(
    const float* __restrict__ x_in, float* __restrict__ e_agg,
    const float* __restrict__ nw1, const float* __restrict__ nb1,
    const float* __restrict__ nw2, const float* __restrict__ nb2,
    const float* __restrict__ pos_in, const float* __restrict__ cu,
    const int* __restrict__ row_ptr,
    float* __restrict__ x_out, float* __restrict__ pos_out,
    const float* __restrict__ Wn, float* __restrict__ P1, float* __restrict__ P2) {
  __shared__ __align__(16) float xT[4][192 * 12];
  const int w = threadIdx.x >> 6, lane = threadIdx.x & 63;
  float* xt = xT[w];
  const int nb = (blockIdx.x * 4 + w) * 8;
#pragma unroll
  for (int e = 0; e < 8; ++e) {
    const int n = nb + e;
    const bool v = n < NN;
    xt[lane * 12 + e]         = v ? x_in[n * HIDC + lane] : 0.f;
    xt[(64 + lane) * 12 + e]  = v ? x_in[n * HIDC + 64 + lane] : 0.f;
    xt[(128 + lane) * 12 + e] = v ? e_agg[n * 64 + lane] : 0.f;
    if (v) e_agg[n * 64 + lane] = 0.f;
  }
  __syncthreads();
  float a[8];
#pragma unroll
  for (int e = 0; e < 8; ++e) a[e] = nb1[lane];
#pragma unroll 2
  for (int k = 0; k < 192; ++k) {
    const float wv = nw1[k * 64 + lane];
    float xk[8];
    *(f32x4*)&xk[0] = *(const f32x4*)&xt[k * 12];
    *(f32x4*)&xk[4] = *(const f32x4*)&xt[k * 12 + 4];
#pragma unroll
    for (int e = 0; e < 8; ++e) a[e] = fmaf(xk[e], wv, a[e]);
  }
#pragma unroll
  for (int e = 0; e < 8; ++e) a[e] = silu_f(a[e]);
  {
    f32x4 t0 = {a[0], a[1], a[2], a[3]};
    f32x4 t1 = {a[4], a[5], a[6], a[7]};
    *(f32x4*)&xt[lane * 12]     = t0;
    *(f32x4*)&xt[lane * 12 + 4] = t1;
  }
  float olo[8], ohi[8];
#pragma unroll
  for (int e = 0; e < 8; ++e) { olo[e] = nb2[lane]; ohi[e] = nb2[64 + lane]; }
#pragma unroll 2
  for (int k = 0; k < 64; ++k) {
    const float wl = nw2[k * HIDC + lane];
    const float wh = nw2[k * HIDC + 64 + lane];
    float hk[8];
    *(f32x4*)&hk[0] = *(const f32x4*)&xt[k * 12];
    *(f32x4*)&hk[4] = *(const f32x4*)&xt[k * 12 + 4];
#pragma unroll
    for (int e = 0; e < 8; ++e) {
      olo[e] = fmaf(hk[e], wl, olo[e]);
      ohi[e] = fmaf(hk[e], wh, ohi[e]);
    }
  }
#pragma unroll
  for (int e = 0; e < 8; ++e) {
    const int n = nb + e;
    if (n < NN) {
      x_out[n * HIDC + lane]      = olo[e];
      x_out[n * HIDC + 64 + lane] = ohi[e];
    }
  }
#pragma unroll
  for (int e = 0; e < 8; ++e) {
    const int n = nb + e;
    if (n < NN && lane < 3) {
      const float dg = fmaxf((float)(row_ptr[n + 1] - row_ptr[n]), 1.f);
      pos_out[n * 3 + lane] = pos_in[n * 3 + lane] + cu[n * 3 + lane] / dg;
    }
  }
  // ---- fused layer-1 precompute: stage x1 transposed, P = x1 @ Wn ----
  {
    f32x4 t0 = {olo[0], olo[1], olo[2], olo[3]};
    f32x4 t1 = {olo[4], olo[5], olo[6], olo[7]};
    *(f32x4*)&xt[lane * 12]     = t0;
    *(f32x4*)&xt[lane * 12 + 4] = t1;
    f32x4 t2 = {ohi[0], ohi[1], ohi[2], ohi[3]};
    f32x4 t3 = {ohi[4], ohi[5], ohi[6], ohi[7]};
    *(f32x4*)&xt[(64 + lane) * 12]     = t2;
    *(f32x4*)&xt[(64 + lane) * 12 + 4] = t3;
  }
  float a1[8], a2[8];
#pragma unroll
  for (int e = 0; e < 8; ++e) { a1[e] = 0.f; a2[e] = 0.f; }
#pragma unroll 4
  for (int k = 0; k < 128; ++k) {
    const float wa = Wn[k * 64 + lane];
    const float wb2 = Wn[(128 + k) * 64 + lane];
    float xk[8];
    *(f32x4*)&xk[0] = *(const f32x4*)&xt[k * 12];
    *(f32x4*)&xk[4] = *(const f32x4*)&xt[k * 12 + 4];
#pragma unroll
    for (int e = 0; e < 8; ++e) {
      a1[e] = fmaf(xk[e], wa, a1[e]);
      a2[e] = fmaf(xk[e], wb2, a2[e]);
    }
  }
#pragma unroll
  for (int e = 0; e < 8; ++e) {
    const int n = nb + e;
    if (n < NN) {
      P1[n * 64 + lane] = a1[e];
      P2[n * 64 + lane] = a2[e];
    }
  }
}

// ------- K3b: layer-1 node MLP + fused batch mean-pool partials ----------------
__global__ __launch_bounds__(256) void k_node_l1(
    const float* __restrict__ x_in, const float* __restrict__ e_agg,
    const float* __restrict__ nw1, const float* __restrict__ nb1,
    const float* __restrict__ nw2, const float* __restrict__ nb2,
    const int* __restrict__ batch,
    float* __restrict__ g_sum, float* __restrict__ g_cnt) {
  __shared__ __align__(16) float xT[4][192 * 12];
  const int w = threadIdx.x >> 6, lane = threadIdx.x & 63;
  float* xt = xT[w];
  const int nb = (blockIdx.x * 4 + w) * 8;
#pragma unroll
  for (int e = 0; e < 8; ++e) {
    const int n = nb + e;
    const bool v = n < NN;
    xt[lane * 12 + e]         = v ? x_in[n * HIDC + lane] : 0.f;
    xt[(64 + lane) * 12 + e]  = v ? x_in[n * HIDC + 64 + lane] : 0.f;
    xt[(128 + lane) * 12 + e] = v ? e_agg[n * 64 + lane] : 0.f;
  }
  __syncthreads();
  float a[8];
#pragma unroll
  for (int e = 0; e < 8; ++e) a[e] = nb1[lane];
#pragma unroll 2
  for (int k = 0; k < 192; ++k) {
    const float wv = nw1[k * 64 + lane];
    float xk[8];
    *(f32x4*)&xk[0] = *(const f32x4*)&xt[k * 12];
    *(f32x4*)&xk[4] = *(const f32x4*)&xt[k * 12 + 4];
#pragma unroll
    for (int e = 0; e < 8; ++e) a[e] = fmaf(xk[e], wv, a[e]);
  }
#pragma unroll
  for (int e = 0; e < 8; ++e) a[e] = silu_f(a[e]);
  {
    f32x4 t0 = {a[0], a[1], a[2], a[3]};
    f32x4 t1 = {a[4], a[5], a[6], a[7]};
    *(f32x4*)&xt[lane * 12]     = t0;
    *(f32x4*)&xt[lane * 12 + 4] = t1;
  }
  float olo[8], ohi[8];
#pragma unroll
  for (int e = 0; e < 8; ++e) { olo[e] = nb2[lane]; ohi[e] = nb2[64 + lane]; }
#pragma unroll 2
  for (int k = 0; k < 64; ++k) {
    const float wl = nw2[k * HIDC + lane];
    const float wh = nw2[k * HIDC + 64 + lane];
    float hk[8];
    *(f32x4*)&hk[0] = *(const f32x4*)&xt[k * 12];
    *(f32x4*)&hk[4] = *(const f32x4*)&xt[k * 12 + 4];
#pragma unroll
    for (int e = 0; e < 8; ++e) {
      olo[e] = fmaf(hk[e], wl, olo[e]);
      ohi[e] = fmaf(hk[e], wh, ohi[e]);
    }
  }
  // fused pooling: batch is sorted -> run-compress per wave
  int curb = -1;
  float accL = 0.f, accH = 0.f, c = 0.f;
#pragma unroll
  for (int e = 0; e < 8; ++e) {
    const int n = nb + e;
    if (n < NN) {
      const int bg = batch[n];
      if (bg != curb) {
        if (curb >= 0) {
          atomicAdd(&g_sum[curb * HIDC + lane], accL);
          atomicAdd(&g_sum[curb * HIDC + 64 + lane], accH);
          if (lane == 0) atomicAdd(&g_cnt[curb], c);
        }
        curb = bg; accL = olo[e]; accH = ohi[e]; c = 1.f;
      } else {
        accL += olo[e]; accH += ohi[e]; c += 1.f;
      }
    }
  }
  if (curb >= 0) {
    atomicAdd(&g_sum[curb * HIDC + lane], accL);
    atomicAdd(&g_sum[curb * HIDC + 64 + lane], accH);
    if (lane == 0) atomicAdd(&g_cnt[curb], c);
  }
}

// ---------------- K5: relu(mean) -> relu(@w1+b1) -> @w2+b2 ----------------
__global__ __launch_bounds__(128) void k_final(
    const float* __restrict__ g_sum, const float* __restrict__ g_cnt,
    const float* __restrict__ w1, const float* __restrict__ b1,
    const float* __restrict__ w2, const float* __restrict__ b2,
    float* __restrict__ out) {
  __shared__ float sg[128];
  __shared__ float sh[128];
  const int g = blockIdx.x, j = threadIdx.x;
  const float c = fmaxf(g_cnt[g], 1.f);
  sg[j] = fmaxf(g_sum[g * HIDC + j] / c, 0.f);
  __syncthreads();
  float a = b1[j];
  for (int k = 0; k < 128; ++k) a += sg[k] * w1[k * 128 + j];
  sh[j] = fmaxf(a, 0.f);
  __syncthreads();
  if (j < OUTC) {
    float o = b2[j];
    for (int k = 0; k < 128; ++k) o += sh[k] * w2[k * OUTC + j];
    out[g * OUTC + j] = o;
  }
}

extern "C" void kernel_launch(void* const* d_in, const int* in_sizes, int n_in,
                              void* d_out, int out_size, void* d_ws, size_t ws_size,
                              hipStream_t stream) {
  const float* x     = (const float*)d_in[0];
  const float* pos   = (const float*)d_in[1];
  const float* eattr = (const float*)d_in[2];
  const int*   ei    = (const int*)d_in[3];
  const int*   batch = (const int*)d_in[4];
  const float* mlp_w[2]   = {(const float*)d_in[5],  (const float*)d_in[14]};
  const float* edge_w[2]  = {(const float*)d_in[6],  (const float*)d_in[15]};
  const float* edge_b[2]  = {(const float*)d_in[7],  (const float*)d_in[16]};
  const float* coord_w[2] = {(const float*)d_in[8],  (const float*)d_in[17]};
  const float* coord_b[2] = {(const float*)d_in[9],  (const float*)d_in[18]};
  const float* nw1[2]     = {(const float*)d_in[10], (const float*)d_in[19]};
  const float* nb1[2]     = {(const float*)d_in[11], (const float*)d_in[20]};
  const float* nw2[2]     = {(const float*)d_in[12], (const float*)d_in[21]};
  const float* nb2[2]     = {(const float*)d_in[13], (const float*)d_in[22]};
  const float* ow1 = (const float*)d_in[23];
  const float* ob1 = (const float*)d_in[24];
  const float* ow2 = (const float*)d_in[25];
  const float* ob2 = (const float*)d_in[26];
  float* out = (float*)d_out;

  char* p = (char*)d_ws;
  auto alloc = [&](size_t bytes) {
    void* r = (void*)p;
    p += (bytes + 255) & ~(size_t)255;
    return r;
  };
  float* P1     = (float*)alloc((size_t)NN * 64 * 4);
  float* P2     = (float*)alloc((size_t)NN * 64 * 4);
  float* e_agg  = (float*)alloc((size_t)NN * 64 * 4);
  float* cu     = (float*)alloc((size_t)NN * 3 * 4);
  float* x1     = (float*)alloc((size_t)NN * HIDC * 4);
  float* pos1   = (float*)alloc((size_t)NN * 3 * 4);
  float* g_sum  = (float*)alloc((size_t)GG * HIDC * 4);
  float* g_cnt  = (float*)alloc((size_t)GG * 4);
  int* cnt      = (int*)alloc((size_t)NN * 4);
  int* row_ptr  = (int*)alloc((size_t)(NN + 1) * 4);
  int* nxt      = (int*)alloc((size_t)NN * 4);
  int* sdst     = (int*)alloc((size_t)EE * 4);
  int* ssrc     = (int*)alloc((size_t)EE * 4);
  float* seattr = (float*)alloc((size_t)EE * DD * 4);

  const int nodeBlocks = (NN + 31) / 32;
  const int edgeBlocks = 1250;  // 1250 x 320 = 400000 exact

  (void)hipMemsetAsync(e_agg, 0, (size_t)NN * 64 * 4, stream);
  (void)hipMemsetAsync(cu,    0, (size_t)NN * 3 * 4, stream);
  (void)hipMemsetAsync(g_sum, 0, (size_t)GG * HIDC * 4, stream);
  (void)hipMemsetAsync(g_cnt, 0, (size_t)GG * 4, stream);
  (void)hipMemsetAsync(cnt,   0, (size_t)NN * 4, stream);

  // ---- build dst-sorted edge order + sorted eattr (shared by both layers) ----
  k_hist<<<(EE + 255) / 256, 256, 0, stream>>>(ei, cnt);
  k_scan<<<1, 1024, 0, stream>>>(cnt, row_ptr, nxt);
  k_scatter<<<(EE + 255) / 256, 256, 0, stream>>>(ei, eattr, nxt, sdst, ssrc, seattr);

  // ---- layer 0 ----
  k_precompute<<<nodeBlocks, 256, 0, stream>>>(x, mlp_w[0], P1, P2);
  k_edge<true><<<edgeBlocks, 256, 0, stream>>>(P1, P2, pos, seattr, sdst, ssrc,
      mlp_w[0], edge_w[0], edge_b[0], coord_w[0], coord_b[0], e_agg, cu);
  k_node_l0<<<nodeBlocks, 256, 0, stream>>>(x, e_agg, nw1[0], nb1[0],
      nw2[0], nb2[0], pos, cu, row_ptr, x1, pos1, mlp_w[1], P1, P2);

  // ---- layer 1 (pos output unused; e_agg pre-zeroed; P1/P2 precomputed) ----
  k_edge<false><<<edgeBlocks, 256, 0, stream>>>(P1, P2, pos1, seattr, sdst, ssrc,
      mlp_w[1], edge_w[1], edge_b[1], coord_w[1], coord_b[1], e_agg, cu);
  k_node_l1<<<nodeBlocks, 256, 0, stream>>>(x1, e_agg, nw1[1], nb1[1],
      nw2[1], nb2[1], batch, g_sum, g_cnt);

  // ---- head ----
  k_final<<<GG, 128, 0, stream>>>(g_sum, g_cnt, ow1, ob1, ow2, ob2, out);
}

// Round 8
// 660.824 us; speedup vs baseline: 1.0155x; 1.0155x over previous
//
#include <hip/hip_runtime.h>
#include <math.h>

#define NN 25000
#define EE 400000
#define FF 128
#define DD 16
#define HH 64
#define HIDC 128
#define OUTC 32
#define GG 64

typedef __attribute__((ext_vector_type(8))) short short8;
typedef __attribute__((ext_vector_type(4))) float f32x4;

union S8 { short8 v; unsigned short u[8]; };

__device__ __forceinline__ float silu_f(float v) {
    return v / (1.f + __expf(-v));
}

__device__ __forceinline__ unsigned short f2bf_rne(float f) {
  unsigned u = __float_as_uint(f);
  unsigned r = u + 0x7fffu + ((u >> 16) & 1u);
  return (unsigned short)(r >> 16);
}
__device__ __forceinline__ float bfbits2f(unsigned short b) {
  return __uint_as_float(((unsigned)b) << 16);
}

// ---------------- Sort: counting sort of edges by dst ----------------
__global__ __launch_bounds__(256) void k_hist(
    const int* __restrict__ ei, int* __restrict__ cnt) {
  const int t = blockIdx.x * 256 + threadIdx.x;
  if (t < EE) atomicAdd(&cnt[ei[EE + t]], 1);
}

__global__ __launch_bounds__(1024) void k_scan(
    const int* __restrict__ cnt, int* __restrict__ row_ptr, int* __restrict__ next) {
  __shared__ int s[1024];
  const int t = threadIdx.x;
  const int base = t * 25;
  int loc[25];
  int sum = 0;
#pragma unroll
  for (int i = 0; i < 25; ++i) {
    const int n = base + i;
    loc[i] = (n < NN) ? cnt[n] : 0;
    sum += loc[i];
  }
  s[t] = sum;
  __syncthreads();
  for (int off = 1; off < 1024; off <<= 1) {
    const int v = (t >= off) ? s[t - off] : 0;
    __syncthreads();
    s[t] += v;
    __syncthreads();
  }
  int run = s[t] - sum;
#pragma unroll
  for (int i = 0; i < 25; ++i) {
    const int n = base + i;
    if (n < NN) {
      row_ptr[n] = run;
      next[n] = run;
      run += loc[i];
    }
  }
  if (t == 0) row_ptr[NN] = EE;
}

// scatter edges into dst-sorted order; also pre-gather eattr rows into sorted order
__global__ __launch_bounds__(256) void k_scatter(
    const int* __restrict__ ei, const float* __restrict__ eattr, int* __restrict__ next,
    int* __restrict__ sdst, int* __restrict__ ssrc, float* __restrict__ seattr) {
  const int t = blockIdx.x * 256 + threadIdx.x;
  if (t < EE) {
    const int d = ei[EE + t];
    const int slot = atomicAdd(&next[d], 1);
    sdst[slot] = d;
    ssrc[slot] = ei[t];
    const f32x4* s4 = (const f32x4*)&eattr[(size_t)t * DD];
    f32x4* d4 = (f32x4*)&seattr[(size_t)slot * DD];
    d4[0] = s4[0]; d4[1] = s4[1]; d4[2] = s4[2]; d4[3] = s4[3];
  }
}

// ---------------- K1: P1 = X @ W[0:128,:], P2 = X @ W[128:256,:] ----------------
__global__ __launch_bounds__(256) void k_precompute(
    const float* __restrict__ X, const float* __restrict__ W,
    float* __restrict__ P1, float* __restrict__ P2) {
  __shared__ __align__(16) float xT[4][128 * 12];
  const int w = threadIdx.x >> 6, lane = threadIdx.x & 63;
  float* xt = xT[w];
  const int nb = (blockIdx.x * 4 + w) * 8;
#pragma unroll
  for (int e = 0; e < 8; ++e) {
    const int n = nb + e;
    const bool v = n < NN;
    xt[lane * 12 + e]        = v ? X[n * FF + lane] : 0.f;
    xt[(lane + 64) * 12 + e] = v ? X[n * FF + 64 + lane] : 0.f;
  }
  __syncthreads();
  float a1[8], a2[8];
#pragma unroll
  for (int e = 0; e < 8; ++e) { a1[e] = 0.f; a2[e] = 0.f; }
#pragma unroll 4
  for (int k = 0; k < 128; ++k) {
    const float wa = W[k * 64 + lane];
    const float wb = W[(128 + k) * 64 + lane];
    float xk[8];
    *(f32x4*)&xk[0] = *(const f32x4*)&xt[k * 12];
    *(f32x4*)&xk[4] = *(const f32x4*)&xt[k * 12 + 4];
#pragma unroll
    for (int e = 0; e < 8; ++e) {
      a1[e] = fmaf(xk[e], wa, a1[e]);
      a2[e] = fmaf(xk[e], wb, a2[e]);
    }
  }
#pragma unroll
  for (int e = 0; e < 8; ++e) {
    const int n = nb + e;
    if (n < NN) {
      P1[n * 64 + lane] = a1[e];
      P2[n * 64 + lane] = a2[e];
    }
  }
}

// ---------------- K2: per-edge MLP via MFMA, dst-sorted, identity dispatch ------
// 1250 blocks x 320 edges, 6 blocks/CU -> all co-resident, no tail.
// NOTE: R7's XCD swizzle REGRESSED (FETCH 157->350MB): workgroup->XCD mapping
// is NOT b%8 on this device. Identity ordering restores dst-run L2 locality.
template <bool COORD>
__global__ __launch_bounds__(256, 6) void k_edge(
    const float* __restrict__ P1, const float* __restrict__ P2,
    const float* __restrict__ pos, const float* __restrict__ seattr,
    const int* __restrict__ sdst, const int* __restrict__ ssrc,
    const float* __restrict__ mlp_w,
    const float* __restrict__ edge_w, const float* __restrict__ edge_b,
    const float* __restrict__ coord_w, const float* __restrict__ coord_b,
    float* __restrict__ e_agg, float* __restrict__ cu) {
  __shared__ int s_src[320], s_dst[320];
  __shared__ __align__(16) float s_hs[4][16 * 76];
  __shared__ float s_diff[4][48];
  __shared__ float s_rad[4][16];
  __shared__ float s_red[4][16];
  const int tid = threadIdx.x, w = tid >> 6, lane = tid & 63;
  const int q = lane >> 4, m = lane & 15;
  const int base = blockIdx.x * 320;
  for (int t = tid; t < 320; t += 256) {
    s_src[t] = ssrc[base + t];
    s_dst[t] = sdst[base + t];
  }
  __syncthreads();

  S8 wB[2][4];
#pragma unroll
  for (int kc = 0; kc < 2; ++kc)
#pragma unroll
    for (int nc = 0; nc < 4; ++nc)
#pragma unroll
      for (int j = 0; j < 8; ++j)
        wB[kc][nc].u[j] = f2bf_rne(edge_w[(kc * 32 + q * 8 + j) * 64 + nc * 16 + m]);
  S8 w3B[4];
#pragma unroll
  for (int nc = 0; nc < 4; ++nc)
#pragma unroll
    for (int j = 0; j < 8; ++j)
      w3B[nc].u[j] = (lane < 32) ? f2bf_rne(mlp_w[256 * 64 + (q * 8 + j) * 64 + nc * 16 + m])
                                 : (unsigned short)0;
  float w4r[4], cwr[4], ebr[4];
#pragma unroll
  for (int nc = 0; nc < 4; ++nc) {
    w4r[nc] = mlp_w[272 * 64 + nc * 16 + m];
    ebr[nc] = edge_b[nc * 16 + m];
    cwr[nc] = COORD ? coord_w[nc * 16 + m] : 0.f;
  }
  const float cb = COORD ? coord_b[0] : 0.f;

  const int wb = w * 80;
  const int pe = (lane < 48) ? (lane / 3) : 0;
  const int pc = lane - (lane / 3) * 3;

  int cur_dst = -1;
  float accum = 0.f;

  for (int g = 0; g < 5; ++g) {
    const int gb = wb + g * 16;
    const int dm = s_dst[gb + m];
    const int sm = s_src[gb + m];
    f32x4 p1a[2], p1b[2], p2a[2], p2b[2];
#pragma unroll
    for (int kc = 0; kc < 2; ++kc) {
      const float* pp1 = P1 + (size_t)dm * 64 + kc * 32 + q * 8;
      const float* pp2 = P2 + (size_t)sm * 64 + kc * 32 + q * 8;
      p1a[kc] = *(const f32x4*)pp1;
      p1b[kc] = *(const f32x4*)(pp1 + 4);
      p2a[kc] = *(const f32x4*)pp2;
      p2b[kc] = *(const f32x4*)(pp2 + 4);
    }
    if (lane < 48) {
      const int de = s_dst[gb + pe], se = s_src[gb + pe];
      s_diff[w][lane] = pos[de * 3 + pc] - pos[se * 3 + pc];
    }
    float ea[8] = {0.f, 0.f, 0.f, 0.f, 0.f, 0.f, 0.f, 0.f};
    if (lane < 32) {
      const float* ep = &seattr[(size_t)(base + gb + m) * DD + q * 8];
      *(f32x4*)&ea[0] = *(const f32x4*)ep;
      *(f32x4*)&ea[4] = *(const f32x4*)(ep + 4);
    }
    S8 eaA;
#pragma unroll
    for (int j = 0; j < 8; ++j) eaA.u[j] = f2bf_rne(ea[j]);
    if (lane < 16) {
      const float d0 = s_diff[w][lane * 3 + 0];
      const float d1 = s_diff[w][lane * 3 + 1];
      const float d2 = s_diff[w][lane * 3 + 2];
      s_rad[w][lane] = fmaf(d0, d0, fmaf(d1, d1, d2 * d2));
    }
    float radr[4];
#pragma unroll
    for (int r = 0; r < 4; ++r) radr[r] = s_rad[w][q * 4 + r];
    f32x4 c3[4];
#pragma unroll
    for (int nc = 0; nc < 4; ++nc) {
      f32x4 z = {0.f, 0.f, 0.f, 0.f};
      c3[nc] = __builtin_amdgcn_mfma_f32_16x16x32_bf16(eaA.v, w3B[nc].v, z, 0, 0, 0);
    }
#pragma unroll
    for (int nc = 0; nc < 4; ++nc)
#pragma unroll
      for (int r = 0; r < 4; ++r)
        s_hs[w][(q * 4 + r) * 76 + nc * 16 + m] = fmaf(radr[r], w4r[nc], c3[nc][r]);
    S8 ahi[2], alo[2];
#pragma unroll
    for (int kc = 0; kc < 2; ++kc) {
      const float* hp = &s_hs[w][m * 76 + kc * 32 + q * 8];
      f32x4 h0 = *(const f32x4*)hp;
      f32x4 h1 = *(const f32x4*)(hp + 4);
      h0 = h0 + p1a[kc] + p2a[kc];
      h1 = h1 + p1b[kc] + p2b[kc];
      float hv[8];
      *(f32x4*)&hv[0] = h0;
      *(f32x4*)&hv[4] = h1;
#pragma unroll
      for (int j = 0; j < 8; ++j) {
        const float h = silu_f(hv[j]);
        const unsigned short hb = (unsigned short)(__float_as_uint(h) >> 16);
        ahi[kc].u[j] = hb;
        alo[kc].u[j] = f2bf_rne(h - bfbits2f(hb));
      }
    }
    f32x4 o[4];
#pragma unroll
    for (int nc = 0; nc < 4; ++nc) {
      f32x4 bi = {ebr[nc], ebr[nc], ebr[nc], ebr[nc]};
      o[nc] = bi;
    }
#pragma unroll
    for (int kc = 0; kc < 2; ++kc)
#pragma unroll
      for (int nc = 0; nc < 4; ++nc) {
        o[nc] = __builtin_amdgcn_mfma_f32_16x16x32_bf16(ahi[kc].v, wB[kc][nc].v, o[nc], 0, 0, 0);
        o[nc] = __builtin_amdgcn_mfma_f32_16x16x32_bf16(alo[kc].v, wB[kc][nc].v, o[nc], 0, 0, 0);
      }
#pragma unroll
    for (int nc = 0; nc < 4; ++nc)
#pragma unroll
      for (int r = 0; r < 4; ++r) o[nc][r] = silu_f(o[nc][r]);
    if (COORD) {
#pragma unroll
      for (int r = 0; r < 4; ++r) {
        float v = o[0][r] * cwr[0] + o[1][r] * cwr[1] + o[2][r] * cwr[2] + o[3][r] * cwr[3];
        v += __shfl_xor(v, 1, 64);
        v += __shfl_xor(v, 2, 64);
        v += __shfl_xor(v, 4, 64);
        v += __shfl_xor(v, 8, 64);
        if (m == 0) s_red[w][q * 4 + r] = v;
      }
    }
#pragma unroll
    for (int nc = 0; nc < 4; ++nc)
#pragma unroll
      for (int r = 0; r < 4; ++r)
        s_hs[w][(q * 4 + r) * 76 + nc * 16 + m] = o[nc][r];
    for (int e = 0; e < 16; ++e) {
      const int dv = s_dst[gb + e];
      const float v = s_hs[w][e * 76 + lane];
      if (dv == cur_dst) {
        accum += v;
      } else {
        if (cur_dst >= 0) atomicAdd(&e_agg[(size_t)cur_dst * 64 + lane], accum);
        cur_dst = dv;
        accum = v;
      }
    }
    if (COORD) {
      if (lane < 48) {
        const float s = silu_f(s_red[w][pe] + cb);
        atomicAdd(&cu[(size_t)s_dst[gb + pe] * 3 + pc], s_diff[w][lane] * s);
      }
    }
  }
  if (cur_dst >= 0) atomicAdd(&e_agg[(size_t)cur_dst * 64 + lane], accum);
}

// ------- K3a: layer-0 node MLP + pos update + e_agg rezero + layer-1 precompute -
__global__ __launch_bounds__(256) void k_node_l0(
    const float* __restrict__ x_in, float* __restrict__ e_agg,
    const float* __restrict__ nw1, const float* __restrict__ nb1,
    const float* __restrict__ nw2, const float* __restrict__ nb2,
    const float* __restrict__ pos_in, const float* __restrict__ cu,
    const int* __restrict__ row_ptr,
    float* __restrict__ x_out, float* __restrict__ pos_out,
    const float* __restrict__ Wn, float* __restrict__ P1, float* __restrict__ P2) {
  __shared__ __align__(16) float xT[4][192 * 12];
  const int w = threadIdx.x >> 6, lane = threadIdx.x & 63;
  float* xt = xT[w];
  const int nb = (blockIdx.x * 4 + w) * 8;
#pragma unroll
  for (int e = 0; e < 8; ++e) {
    const int n = nb + e;
    const bool v = n < NN;
    xt[lane * 12 + e]         = v ? x_in[n * HIDC + lane] : 0.f;
    xt[(64 + lane) * 12 + e]  = v ? x_in[n * HIDC + 64 + lane] : 0.f;
    xt[(128 + lane) * 12 + e] = v ? e_agg[n * 64 + lane] : 0.f;
    if (v) e_agg[n * 64 + lane] = 0.f;
  }
  __syncthreads();
  float a[8];
#pragma unroll
  for (int e = 0; e < 8; ++e) a[e] = nb1[lane];
#pragma unroll 2
  for (int k = 0; k < 192; ++k) {
    const float wv = nw1[k * 64 + lane];
    float xk[8];
    *(f32x4*)&xk[0] = *(const f32x4*)&xt[k * 12];
    *(f32x4*)&xk[4] = *(const f32x4*)&xt[k * 12 + 4];
#pragma unroll
    for (int e = 0; e < 8; ++e) a[e] = fmaf(xk[e], wv, a[e]);
  }
#pragma unroll
  for (int e = 0; e < 8; ++e) a[e] = silu_f(a[e]);
  {
    f32x4 t0 = {a[0], a[1], a[2], a[3]};
    f32x4 t1 = {a[4], a[5], a[6], a[7]};
    *(f32x4*)&xt[lane * 12]     = t0;
    *(f32x4*)&xt[lane * 12 + 4] = t1;
  }
  float olo[8], ohi[8];
#pragma unroll
  for (int e = 0; e < 8; ++e) { olo[e] = nb2[lane]; ohi[e] = nb2[64 + lane]; }
#pragma unroll 2
  for (int k = 0; k < 64; ++k) {
    const float wl = nw2[k * HIDC + lane];
    const float wh = nw2[k * HIDC + 64 + lane];
    float hk[8];
    *(f32x4*)&hk[0] = *(const f32x4*)&xt[k * 12];
    *(f32x4*)&hk[4] = *(const f32x4*)&xt[k * 12 + 4];
#pragma unroll
    for (int e = 0; e < 8; ++e) {
      olo[e] = fmaf(hk[e], wl, olo[e]);
      ohi[e] = fmaf(hk[e], wh, ohi[e]);
    }
  }
#pragma unroll
  for (int e = 0; e < 8; ++e) {
    const int n = nb + e;
    if (n < NN) {
      x_out[n * HIDC + lane]      = olo[e];
      x_out[n * HIDC + 64 + lane] = ohi[e];
    }
  }
#pragma unroll
  for (int e = 0; e < 8; ++e) {
    const int n = nb + e;
    if (n < NN && lane < 3) {
      const float dg = fmaxf((float)(row_ptr[n + 1] - row_ptr[n]), 1.f);
      pos_out[n * 3 + lane] = pos_in[n * 3 + lane] + cu[n * 3 + lane] / dg;
    }
  }
  // ---- fused layer-1 precompute: stage x1 transposed, P = x1 @ Wn ----
  {
    f32x4 t0 = {olo[0], olo[1], olo[2], olo[3]};
    f32x4 t1 = {olo[4], olo[5], olo[6], olo[7]};
    *(f32x4*)&xt[lane * 12]     = t0;
    *(f32x4*)&xt[lane * 12 + 4] = t1;
    f32x4 t2 = {ohi[0], ohi[1], ohi[2], ohi[3]};
    f32x4 t3 = {ohi[4], ohi[5], ohi[6], ohi[7]};
    *(f32x4*)&xt[(64 + lane) * 12]     = t2;
    *(f32x4*)&xt[(64 + lane) * 12 + 4] = t3;
  }
  float a1[8], a2[8];
#pragma unroll
  for (int e = 0; e < 8; ++e) { a1[e] = 0.f; a2[e] = 0.f; }
#pragma unroll 4
  for (int k = 0; k < 128; ++k) {
    const float wa = Wn[k * 64 + lane];
    const float wb2 = Wn[(128 + k) * 64 + lane];
    float xk[8];
    *(f32x4*)&xk[0] = *(const f32x4*)&xt[k * 12];
    *(f32x4*)&xk[4] = *(const f32x4*)&xt[k * 12 + 4];
#pragma unroll
    for (int e = 0; e < 8; ++e) {
      a1[e] = fmaf(xk[e], wa, a1[e]);
      a2[e] = fmaf(xk[e], wb2, a2[e]);
    }
  }
#pragma unroll
  for (int e = 0; e < 8; ++e) {
    const int n = nb + e;
    if (n < NN) {
      P1[n * 64 + lane] = a1[e];
      P2[n * 64 + lane] = a2[e];
    }
  }
}

// ------- K3b: layer-1 node MLP + fused batch mean-pool partials ----------------
__global__ __launch_bounds__(256) void k_node_l1(
    const float* __restrict__ x_in, const float* __restrict__ e_agg,
    const float* __restrict__ nw1, const float* __restrict__ nb1,
    const float* __restrict__ nw2, const float* __restrict__ nb2,
    const int* __restrict__ batch,
    float* __restrict__ g_sum, float* __restrict__ g_cnt) {
  __shared__ __align__(16) float xT[4][192 * 12];
  const int w = threadIdx.x >> 6, lane = threadIdx.x & 63;
  float* xt = xT[w];
  const int nb = (blockIdx.x * 4 + w) * 8;
#pragma unroll
  for (int e = 0; e < 8; ++e) {
    const int n = nb + e;
    const bool v = n < NN;
    xt[lane * 12 + e]         = v ? x_in[n * HIDC + lane] : 0.f;
    xt[(64 + lane) * 12 + e]  = v ? x_in[n * HIDC + 64 + lane] : 0.f;
    xt[(128 + lane) * 12 + e] = v ? e_agg[n * 64 + lane] : 0.f;
  }
  __syncthreads();
  float a[8];
#pragma unroll
  for (int e = 0; e < 8; ++e) a[e] = nb1[lane];
#pragma unroll 2
  for (int k = 0; k < 192; ++k) {
    const float wv = nw1[k * 64 + lane];
    float xk[8];
    *(f32x4*)&xk[0] = *(const f32x4*)&xt[k * 12];
    *(f32x4*)&xk[4] = *(const f32x4*)&xt[k * 12 + 4];
#pragma unroll
    for (int e = 0; e < 8; ++e) a[e] = fmaf(xk[e], wv, a[e]);
  }
#pragma unroll
  for (int e = 0; e < 8; ++e) a[e] = silu_f(a[e]);
  {
    f32x4 t0 = {a[0], a[1], a[2], a[3]};
    f32x4 t1 = {a[4], a[5], a[6], a[7]};
    *(f32x4*)&xt[lane * 12]     = t0;
    *(f32x4*)&xt[lane * 12 + 4] = t1;
  }
  float olo[8], ohi[8];
#pragma unroll
  for (int e = 0; e < 8; ++e) { olo[e] = nb2[lane]; ohi[e] = nb2[64 + lane]; }
#pragma unroll 2
  for (int k = 0; k < 64; ++k) {
    const float wl = nw2[k * HIDC + lane];
    const float wh = nw2[k * HIDC + 64 + lane];
    float hk[8];
    *(f32x4*)&hk[0] = *(const f32x4*)&xt[k * 12];
    *(f32x4*)&hk[4] = *(const f32x4*)&xt[k * 12 + 4];
#pragma unroll
    for (int e = 0; e < 8; ++e) {
      olo[e] = fmaf(hk[e], wl, olo[e]);
      ohi[e] = fmaf(hk[e], wh, ohi[e]);
    }
  }
  // fused pooling: batch is sorted -> run-compress per wave
  int curb = -1;
  float accL = 0.f, accH = 0.f, c = 0.f;
#pragma unroll
  for (int e = 0; e < 8; ++e) {
    const int n = nb + e;
    if (n < NN) {
      const int bg = batch[n];
      if (bg != curb) {
        if (curb >= 0) {
          atomicAdd(&g_sum[curb * HIDC + lane], accL);
          atomicAdd(&g_sum[curb * HIDC + 64 + lane], accH);
          if (lane == 0) atomicAdd(&g_cnt[curb], c);
        }
        curb = bg; accL = olo[e]; accH = ohi[e]; c = 1.f;
      } else {
        accL += olo[e]; accH += ohi[e]; c += 1.f;
      }
    }
  }
  if (curb >= 0) {
    atomicAdd(&g_sum[curb * HIDC + lane], accL);
    atomicAdd(&g_sum[curb * HIDC + 64 + lane], accH);
    if (lane == 0) atomicAdd(&g_cnt[curb], c);
  }
}

// ---------------- K5: relu(mean) -> relu(@w1+b1) -> @w2+b2 ----------------
__global__ __launch_bounds__(128) void k_final(
    const float* __restrict__ g_sum, const float* __restrict__ g_cnt,
    const float* __restrict__ w1, const float* __restrict__ b1,
    const float* __restrict__ w2, const float* __restrict__ b2,
    float* __restrict__ out) {
  __shared__ float sg[128];
  __shared__ float sh[128];
  const int g = blockIdx.x, j = threadIdx.x;
  const float c = fmaxf(g_cnt[g], 1.f);
  sg[j] = fmaxf(g_sum[g * HIDC + j] / c, 0.f);
  __syncthreads();
  float a = b1[j];
  for (int k = 0; k < 128; ++k) a += sg[k] * w1[k * 128 + j];
  sh[j] = fmaxf(a, 0.f);
  __syncthreads();
  if (j < OUTC) {
    float o = b2[j];
    for (int k = 0; k < 128; ++k) o += sh[k] * w2[k * OUTC + j];
    out[g * OUTC + j] = o;
  }
}

extern "C" void kernel_launch(void* const* d_in, const int* in_sizes, int n_in,
                              void* d_out, int out_size, void* d_ws, size_t ws_size,
                              hipStream_t stream) {
  const float* x     = (const float*)d_in[0];
  const float* pos   = (const float*)d_in[1];
  const float* eattr = (const float*)d_in[2];
  const int*   ei    = (const int*)d_in[3];
  const int*   batch = (const int*)d_in[4];
  const float* mlp_w[2]   = {(const float*)d_in[5],  (const float*)d_in[14]};
  const float* edge_w[2]  = {(const float*)d_in[6],  (const float*)d_in[15]};
  const float* edge_b[2]  = {(const float*)d_in[7],  (const float*)d_in[16]};
  const float* coord_w[2] = {(const float*)d_in[8],  (const float*)d_in[17]};
  const float* coord_b[2] = {(const float*)d_in[9],  (const float*)d_in[18]};
  const float* nw1[2]     = {(const float*)d_in[10], (const float*)d_in[19]};
  const float* nb1[2]     = {(const float*)d_in[11], (const float*)d_in[20]};
  const float* nw2[2]     = {(const float*)d_in[12], (const float*)d_in[21]};
  const float* nb2[2]     = {(const float*)d_in[13], (const float*)d_in[22]};
  const float* ow1 = (const float*)d_in[23];
  const float* ob1 = (const float*)d_in[24];
  const float* ow2 = (const float*)d_in[25];
  const float* ob2 = (const float*)d_in[26];
  float* out = (float*)d_out;

  char* p = (char*)d_ws;
  auto alloc = [&](size_t bytes) {
    void* r = (void*)p;
    p += (bytes + 255) & ~(size_t)255;
    return r;
  };
  float* P1     = (float*)alloc((size_t)NN * 64 * 4);
  float* P2     = (float*)alloc((size_t)NN * 64 * 4);
  float* e_agg  = (float*)alloc((size_t)NN * 64 * 4);
  float* cu     = (float*)alloc((size_t)NN * 3 * 4);
  float* x1     = (float*)alloc((size_t)NN * HIDC * 4);
  float* pos1   = (float*)alloc((size_t)NN * 3 * 4);
  float* g_sum  = (float*)alloc((size_t)GG * HIDC * 4);
  float* g_cnt  = (float*)alloc((size_t)GG * 4);
  int* cnt      = (int*)alloc((size_t)NN * 4);
  int* row_ptr  = (int*)alloc((size_t)(NN + 1) * 4);
  int* nxt      = (int*)alloc((size_t)NN * 4);
  int* sdst     = (int*)alloc((size_t)EE * 4);
  int* ssrc     = (int*)alloc((size_t)EE * 4);
  float* seattr = (float*)alloc((size_t)EE * DD * 4);

  const int nodeBlocks = (NN + 31) / 32;
  const int edgeBlocks = 1250;  // 1250 x 320 = 400000 exact

  (void)hipMemsetAsync(e_agg, 0, (size_t)NN * 64 * 4, stream);
  (void)hipMemsetAsync(cu,    0, (size_t)NN * 3 * 4, stream);
  (void)hipMemsetAsync(g_sum, 0, (size_t)GG * HIDC * 4, stream);
  (void)hipMemsetAsync(g_cnt, 0, (size_t)GG * 4, stream);
  (void)hipMemsetAsync(cnt,   0, (size_t)NN * 4, stream);

  // ---- build dst-sorted edge order + sorted eattr (shared by both layers) ----
  k_hist<<<(EE + 255) / 256, 256, 0, stream>>>(ei, cnt);
  k_scan<<<1, 1024, 0, stream>>>(cnt, row_ptr, nxt);
  k_scatter<<<(EE + 255) / 256, 256, 0, stream>>>(ei, eattr, nxt, sdst, ssrc, seattr);

  // ---- layer 0 ----
  k_precompute<<<nodeBlocks, 256, 0, stream>>>(x, mlp_w[0], P1, P2);
  k_edge<true><<<edgeBlocks, 256, 0, stream>>>(P1, P2, pos, seattr, sdst, ssrc,
      mlp_w[0], edge_w[0], edge_b[0], coord_w[0], coord_b[0], e_agg, cu);
  k_node_l0<<<nodeBlocks, 256, 0, stream>>>(x, e_agg, nw1[0], nb1[0],
      nw2[0], nb2[0], pos, cu, row_ptr, x1, pos1, mlp_w[1], P1, P2);

  // ---- layer 1 (pos output unused; e_agg pre-zeroed; P1/P2 precomputed) ----
  k_edge<false><<<edgeBlocks, 256, 0, stream>>>(P1, P2, pos1, seattr, sdst, ssrc,
      mlp_w[1], edge_w[1], edge_b[1], coord_w[1], coord_b[1], e_agg, cu);
  k_node_l1<<<nodeBlocks, 256, 0, stream>>>(x1, e_agg, nw1[1], nb1[1],
      nw2[1], nb2[1], batch, g_sum, g_cnt);

  // ---- head ----
  k_final<<<GG, 128, 0, stream>>>(g_sum, g_cnt, ow1, ob1, ow2, ob2, out);
}

// Round 9
// 618.682 us; speedup vs baseline: 1.0847x; 1.0681x over previous
//
#include <hip/hip_runtime.h>
#include <math.h>

#define NN 25000
#define EE 400000
#define FF 128
#define DD 16
#define HH 64
#define HIDC 128
#define OUTC 32
#define GG 64

typedef __attribute__((ext_vector_type(8))) short short8;
typedef __attribute__((ext_vector_type(4))) float f32x4;

union S8 { short8 v; unsigned short u[8]; };

__device__ __forceinline__ float silu_f(float v) {
    return v / (1.f + __expf(-v));
}

__device__ __forceinline__ unsigned short f2bf_rne(float f) {
  unsigned u = __float_as_uint(f);
  unsigned r = u + 0x7fffu + ((u >> 16) & 1u);
  return (unsigned short)(r >> 16);
}
__device__ __forceinline__ float bfbits2f(unsigned short b) {
  return __uint_as_float(((unsigned)b) << 16);
}

// ---------------- Sort: counting sort of edges by dst ----------------
__global__ __launch_bounds__(256) void k_hist(
    const int* __restrict__ ei, int* __restrict__ cnt) {
  const int t = blockIdx.x * 256 + threadIdx.x;
  if (t < EE) atomicAdd(&cnt[ei[EE + t]], 1);
}

__global__ __launch_bounds__(1024) void k_scan(
    const int* __restrict__ cnt, int* __restrict__ row_ptr, int* __restrict__ next) {
  __shared__ int s[1024];
  const int t = threadIdx.x;
  const int base = t * 25;
  int loc[25];
  int sum = 0;
#pragma unroll
  for (int i = 0; i < 25; ++i) {
    const int n = base + i;
    loc[i] = (n < NN) ? cnt[n] : 0;
    sum += loc[i];
  }
  s[t] = sum;
  __syncthreads();
  for (int off = 1; off < 1024; off <<= 1) {
    const int v = (t >= off) ? s[t - off] : 0;
    __syncthreads();
    s[t] += v;
    __syncthreads();
  }
  int run = s[t] - sum;
#pragma unroll
  for (int i = 0; i < 25; ++i) {
    const int n = base + i;
    if (n < NN) {
      row_ptr[n] = run;
      next[n] = run;
      run += loc[i];
    }
  }
  if (t == 0) row_ptr[NN] = EE;
}

// scatter edges into dst-sorted order; also pre-gather eattr rows into sorted order
__global__ __launch_bounds__(256) void k_scatter(
    const int* __restrict__ ei, const float* __restrict__ eattr, int* __restrict__ next,
    int* __restrict__ sdst, int* __restrict__ ssrc, float* __restrict__ seattr) {
  const int t = blockIdx.x * 256 + threadIdx.x;
  if (t < EE) {
    const int d = ei[EE + t];
    const int slot = atomicAdd(&next[d], 1);
    sdst[slot] = d;
    ssrc[slot] = ei[t];
    const f32x4* s4 = (const f32x4*)&eattr[(size_t)t * DD];
    f32x4* d4 = (f32x4*)&seattr[(size_t)slot * DD];
    d4[0] = s4[0]; d4[1] = s4[1]; d4[2] = s4[2]; d4[3] = s4[3];
  }
}

// ---------------- K1: P1 = X @ W[0:128,:], P2 = X @ W[128:256,:] ----------------
__global__ __launch_bounds__(256) void k_precompute(
    const float* __restrict__ X, const float* __restrict__ W,
    float* __restrict__ P1, float* __restrict__ P2) {
  __shared__ __align__(16) float xT[4][128 * 12];
  const int w = threadIdx.x >> 6, lane = threadIdx.x & 63;
  float* xt = xT[w];
  const int nb = (blockIdx.x * 4 + w) * 8;
#pragma unroll
  for (int e = 0; e < 8; ++e) {
    const int n = nb + e;
    const bool v = n < NN;
    xt[lane * 12 + e]        = v ? X[n * FF + lane] : 0.f;
    xt[(lane + 64) * 12 + e] = v ? X[n * FF + 64 + lane] : 0.f;
  }
  __syncthreads();
  float a1[8], a2[8];
#pragma unroll
  for (int e = 0; e < 8; ++e) { a1[e] = 0.f; a2[e] = 0.f; }
#pragma unroll 4
  for (int k = 0; k < 128; ++k) {
    const float wa = W[k * 64 + lane];
    const float wb = W[(128 + k) * 64 + lane];
    float xk[8];
    *(f32x4*)&xk[0] = *(const f32x4*)&xt[k * 12];
    *(f32x4*)&xk[4] = *(const f32x4*)&xt[k * 12 + 4];
#pragma unroll
    for (int e = 0; e < 8; ++e) {
      a1[e] = fmaf(xk[e], wa, a1[e]);
      a2[e] = fmaf(xk[e], wb, a2[e]);
    }
  }
#pragma unroll
  for (int e = 0; e < 8; ++e) {
    const int n = nb + e;
    if (n < NN) {
      P1[n * 64 + lane] = a1[e];
      P2[n * 64 + lane] = a2[e];
    }
  }
}

// ---------------- K2: per-edge MLP via MFMA, dst-sorted ------------------------
// 1250 blocks x 320 edges. __launch_bounds__(256,5): 5 blocks/CU -> 1280 slots,
// all blocks co-resident AND VGPR budget ~102 (compiler needs ~64, no spill).
// R7/R8 POST-MORTEM: (256,6) forced VGPR 40 -> scratch spills -> +190MB FETCH,
// +100MB WRITE. The XCD swizzle was innocent (R8 A/B proved it).
template <bool COORD>
__global__ __launch_bounds__(256, 5) void k_edge(
    const float* __restrict__ P1, const float* __restrict__ P2,
    const float* __restrict__ pos, const float* __restrict__ seattr,
    const int* __restrict__ sdst, const int* __restrict__ ssrc,
    const float* __restrict__ mlp_w,
    const float* __restrict__ edge_w, const float* __restrict__ edge_b,
    const float* __restrict__ coord_w, const float* __restrict__ coord_b,
    float* __restrict__ e_agg, float* __restrict__ cu) {
  __shared__ int s_src[320], s_dst[320];
  __shared__ __align__(16) float s_hs[4][16 * 76];
  __shared__ float s_diff[4][48];
  __shared__ float s_rad[4][16];
  __shared__ float s_red[4][16];
  const int tid = threadIdx.x, w = tid >> 6, lane = tid & 63;
  const int q = lane >> 4, m = lane & 15;
  const int base = blockIdx.x * 320;
  for (int t = tid; t < 320; t += 256) {
    s_src[t] = ssrc[base + t];
    s_dst[t] = sdst[base + t];
  }
  __syncthreads();

  S8 wB[2][4];
#pragma unroll
  for (int kc = 0; kc < 2; ++kc)
#pragma unroll
    for (int nc = 0; nc < 4; ++nc)
#pragma unroll
      for (int j = 0; j < 8; ++j)
        wB[kc][nc].u[j] = f2bf_rne(edge_w[(kc * 32 + q * 8 + j) * 64 + nc * 16 + m]);
  S8 w3B[4];
#pragma unroll
  for (int nc = 0; nc < 4; ++nc)
#pragma unroll
    for (int j = 0; j < 8; ++j)
      w3B[nc].u[j] = (lane < 32) ? f2bf_rne(mlp_w[256 * 64 + (q * 8 + j) * 64 + nc * 16 + m])
                                 : (unsigned short)0;
  float w4r[4], cwr[4], ebr[4];
#pragma unroll
  for (int nc = 0; nc < 4; ++nc) {
    w4r[nc] = mlp_w[272 * 64 + nc * 16 + m];
    ebr[nc] = edge_b[nc * 16 + m];
    cwr[nc] = COORD ? coord_w[nc * 16 + m] : 0.f;
  }
  const float cb = COORD ? coord_b[0] : 0.f;

  const int wb = w * 80;
  const int pe = (lane < 48) ? (lane / 3) : 0;
  const int pc = lane - (lane / 3) * 3;

  int cur_dst = -1;
  float accum = 0.f;

  for (int g = 0; g < 5; ++g) {
    const int gb = wb + g * 16;
    const int dm = s_dst[gb + m];
    const int sm = s_src[gb + m];
    f32x4 p1a[2], p1b[2], p2a[2], p2b[2];
#pragma unroll
    for (int kc = 0; kc < 2; ++kc) {
      const float* pp1 = P1 + (size_t)dm * 64 + kc * 32 + q * 8;
      const float* pp2 = P2 + (size_t)sm * 64 + kc * 32 + q * 8;
      p1a[kc] = *(const f32x4*)pp1;
      p1b[kc] = *(const f32x4*)(pp1 + 4);
      p2a[kc] = *(const f32x4*)pp2;
      p2b[kc] = *(const f32x4*)(pp2 + 4);
    }
    if (lane < 48) {
      const int de = s_dst[gb + pe], se = s_src[gb + pe];
      s_diff[w][lane] = pos[de * 3 + pc] - pos[se * 3 + pc];
    }
    float ea[8] = {0.f, 0.f, 0.f, 0.f, 0.f, 0.f, 0.f, 0.f};
    if (lane < 32) {
      const float* ep = &seattr[(size_t)(base + gb + m) * DD + q * 8];
      *(f32x4*)&ea[0] = *(const f32x4*)ep;
      *(f32x4*)&ea[4] = *(const f32x4*)(ep + 4);
    }
    S8 eaA;
#pragma unroll
    for (int j = 0; j < 8; ++j) eaA.u[j] = f2bf_rne(ea[j]);
    if (lane < 16) {
      const float d0 = s_diff[w][lane * 3 + 0];
      const float d1 = s_diff[w][lane * 3 + 1];
      const float d2 = s_diff[w][lane * 3 + 2];
      s_rad[w][lane] = fmaf(d0, d0, fmaf(d1, d1, d2 * d2));
    }
    float radr[4];
#pragma unroll
    for (int r = 0; r < 4; ++r) radr[r] = s_rad[w][q * 4 + r];
    f32x4 c3[4];
#pragma unroll
    for (int nc = 0; nc < 4; ++nc) {
      f32x4 z = {0.f, 0.f, 0.f, 0.f};
      c3[nc] = __builtin_amdgcn_mfma_f32_16x16x32_bf16(eaA.v, w3B[nc].v, z, 0, 0, 0);
    }
#pragma unroll
    for (int nc = 0; nc < 4; ++nc)
#pragma unroll
      for (int r = 0; r < 4; ++r)
        s_hs[w][(q * 4 + r) * 76 + nc * 16 + m] = fmaf(radr[r], w4r[nc], c3[nc][r]);
    S8 ahi[2], alo[2];
#pragma unroll
    for (int kc = 0; kc < 2; ++kc) {
      const float* hp = &s_hs[w][m * 76 + kc * 32 + q * 8];
      f32x4 h0 = *(const f32x4*)hp;
      f32x4 h1 = *(const f32x4*)(hp + 4);
      h0 = h0 + p1a[kc] + p2a[kc];
      h1 = h1 + p1b[kc] + p2b[kc];
      float hv[8];
      *(f32x4*)&hv[0] = h0;
      *(f32x4*)&hv[4] = h1;
#pragma unroll
      for (int j = 0; j < 8; ++j) {
        const float h = silu_f(hv[j]);
        const unsigned short hb = (unsigned short)(__float_as_uint(h) >> 16);
        ahi[kc].u[j] = hb;
        alo[kc].u[j] = f2bf_rne(h - bfbits2f(hb));
      }
    }
    f32x4 o[4];
#pragma unroll
    for (int nc = 0; nc < 4; ++nc) {
      f32x4 bi = {ebr[nc], ebr[nc], ebr[nc], ebr[nc]};
      o[nc] = bi;
    }
#pragma unroll
    for (int kc = 0; kc < 2; ++kc)
#pragma unroll
      for (int nc = 0; nc < 4; ++nc) {
        o[nc] = __builtin_amdgcn_mfma_f32_16x16x32_bf16(ahi[kc].v, wB[kc][nc].v, o[nc], 0, 0, 0);
        o[nc] = __builtin_amdgcn_mfma_f32_16x16x32_bf16(alo[kc].v, wB[kc][nc].v, o[nc], 0, 0, 0);
      }
#pragma unroll
    for (int nc = 0; nc < 4; ++nc)
#pragma unroll
      for (int r = 0; r < 4; ++r) o[nc][r] = silu_f(o[nc][r]);
    if (COORD) {
#pragma unroll
      for (int r = 0; r < 4; ++r) {
        float v = o[0][r] * cwr[0] + o[1][r] * cwr[1] + o[2][r] * cwr[2] + o[3][r] * cwr[3];
        v += __shfl_xor(v, 1, 64);
        v += __shfl_xor(v, 2, 64);
        v += __shfl_xor(v, 4, 64);
        v += __shfl_xor(v, 8, 64);
        if (m == 0) s_red[w][q * 4 + r] = v;
      }
    }
#pragma unroll
    for (int nc = 0; nc < 4; ++nc)
#pragma unroll
      for (int r = 0; r < 4; ++r)
        s_hs[w][(q * 4 + r) * 76 + nc * 16 + m] = o[nc][r];
    for (int e = 0; e < 16; ++e) {
      const int dv = s_dst[gb + e];
      const float v = s_hs[w][e * 76 + lane];
      if (dv == cur_dst) {
        accum += v;
      } else {
        if (cur_dst >= 0) atomicAdd(&e_agg[(size_t)cur_dst * 64 + lane], accum);
        cur_dst = dv;
        accum = v;
      }
    }
    if (COORD) {
      if (lane < 48) {
        const float s = silu_f(s_red[w][pe] + cb);
        atomicAdd(&cu[(size_t)s_dst[gb + pe] * 3 + pc], s_diff[w][lane] * s);
      }
    }
  }
  if (cur_dst >= 0) atomicAdd(&e_agg[(size_t)cur_dst * 64 + lane], accum);
}

// ------- K3a: layer-0 node MLP + pos update + e_agg rezero + layer-1 precompute -
__global__ __launch_bounds__(256) void k_node_l0(
    const float* __restrict__ x_in, float* __restrict__ e_agg,
    const float* __restrict__ nw1, const float* __restrict__ nb1,
    const float* __restrict__ nw2, const float* __restrict__ nb2,
    const float* __restrict__ pos_in, const float* __restrict__ cu,
    const int* __restrict__ row_ptr,
    float* __restrict__ x_out, float* __restrict__ pos_out,
    const float* __restrict__ Wn, float* __restrict__ P1, float* __restrict__ P2) {
  __shared__ __align__(16) float xT[4][192 * 12];
  const int w = threadIdx.x >> 6, lane = threadIdx.x & 63;
  float* xt = xT[w];
  const int nb = (blockIdx.x * 4 + w) * 8;
#pragma unroll
  for (int e = 0; e < 8; ++e) {
    const int n = nb + e;
    const bool v = n < NN;
    xt[lane * 12 + e]         = v ? x_in[n * HIDC + lane] : 0.f;
    xt[(64 + lane) * 12 + e]  = v ? x_in[n * HIDC + 64 + lane] : 0.f;
    xt[(128 + lane) * 12 + e] = v ? e_agg[n * 64 + lane] : 0.f;
    if (v) e_agg[n * 64 + lane] = 0.f;
  }
  __syncthreads();
  float a[8];
#pragma unroll
  for (int e = 0; e < 8; ++e) a[e] = nb1[lane];
#pragma unroll 2
  for (int k = 0; k < 192; ++k) {
    const float wv = nw1[k * 64 + lane];
    float xk[8];
    *(f32x4*)&xk[0] = *(const f32x4*)&xt[k * 12];
    *(f32x4*)&xk[4] = *(const f32x4*)&xt[k * 12 + 4];
#pragma unroll
    for (int e = 0; e < 8; ++e) a[e] = fmaf(xk[e], wv, a[e]);
  }
#pragma unroll
  for (int e = 0; e < 8; ++e) a[e] = silu_f(a[e]);
  {
    f32x4 t0 = {a[0], a[1], a[2], a[3]};
    f32x4 t1 = {a[4], a[5], a[6], a[7]};
    *(f32x4*)&xt[lane * 12]     = t0;
    *(f32x4*)&xt[lane * 12 + 4] = t1;
  }
  float olo[8], ohi[8];
#pragma unroll
  for (int e = 0; e < 8; ++e) { olo[e] = nb2[lane]; ohi[e] = nb2[64 + lane]; }
#pragma unroll 2
  for (int k = 0; k < 64; ++k) {
    const float wl = nw2[k * HIDC + lane];
    const float wh = nw2[k * HIDC + 64 + lane];
    float hk[8];
    *(f32x4*)&hk[0] = *(const f32x4*)&xt[k * 12];
    *(f32x4*)&hk[4] = *(const f32x4*)&xt[k * 12 + 4];
#pragma unroll
    for (int e = 0; e < 8; ++e) {
      olo[e] = fmaf(hk[e], wl, olo[e]);
      ohi[e] = fmaf(hk[e], wh, ohi[e]);
    }
  }
#pragma unroll
  for (int e = 0; e < 8; ++e) {
    const int n = nb + e;
    if (n < NN) {
      x_out[n * HIDC + lane]      = olo[e];
      x_out[n * HIDC + 64 + lane] = ohi[e];
    }
  }
#pragma unroll
  for (int e = 0; e < 8; ++e) {
    const int n = nb + e;
    if (n < NN && lane < 3) {
      const float dg = fmaxf((float)(row_ptr[n + 1] - row_ptr[n]), 1.f);
      pos_out[n * 3 + lane] = pos_in[n * 3 + lane] + cu[n * 3 + lane] / dg;
    }
  }
  // ---- fused layer-1 precompute: stage x1 transposed, P = x1 @ Wn ----
  {
    f32x4 t0 = {olo[0], olo[1], olo[2], olo[3]};
    f32x4 t1 = {olo[4], olo[5], olo[6], olo[7]};
    *(f32x4*)&xt[lane * 12]     = t0;
    *(f32x4*)&xt[lane * 12 + 4] = t1;
    f32x4 t2 = {ohi[0], ohi[1], ohi[2], ohi[3]};
    f32x4 t3 = {ohi[4], ohi[5], ohi[6], ohi[7]};
    *(f32x4*)&xt[(64 + lane) * 12]     = t2;
    *(f32x4*)&xt[(64 + lane) * 12 + 4] = t3;
  }
  float a1[8], a2[8];
#pragma unroll
  for (int e = 0; e < 8; ++e) { a1[e] = 0.f; a2[e] = 0.f; }
#pragma unroll 4
  for (int k = 0; k < 128; ++k) {
    const float wa = Wn[k * 64 + lane];
    const float wb2 = Wn[(128 + k) * 64 + lane];
    float xk[8];
    *(f32x4*)&xk[0] = *(const f32x4*)&xt[k * 12];
    *(f32x4*)&xk[4] = *(const f32x4*)&xt[k * 12 + 4];
#pragma unroll
    for (int e = 0; e < 8; ++e) {
      a1[e] = fmaf(xk[e], wa, a1[e]);
      a2[e] = fmaf(xk[e], wb2, a2[e]);
    }
  }
#pragma unroll
  for (int e = 0; e < 8; ++e) {
    const int n = nb + e;
    if (n < NN) {
      P1[n * 64 + lane] = a1[e];
      P2[n * 64 + lane] = a2[e];
    }
  }
}

// ------- K3b: layer-1 node MLP + fused batch mean-pool partials ----------------
__global__ __launch_bounds__(256) void k_node_l1(
    const float* __restrict__ x_in, const float* __restrict__ e_agg,
    const float* __restrict__ nw1, const float* __restrict__ nb1,
    const float* __restrict__ nw2, const float* __restrict__ nb2,
    const int* __restrict__ batch,
    float* __restrict__ g_sum, float* __restrict__ g_cnt) {
  __shared__ __align__(16) float xT[4][192 * 12];
  const int w = threadIdx.x >> 6, lane = threadIdx.x & 63;
  float* xt = xT[w];
  const int nb = (blockIdx.x * 4 + w) * 8;
#pragma unroll
  for (int e = 0; e < 8; ++e) {
    const int n = nb + e;
    const bool v = n < NN;
    xt[lane * 12 + e]         = v ? x_in[n * HIDC + lane] : 0.f;
    xt[(64 + lane) * 12 + e]  = v ? x_in[n * HIDC + 64 + lane] : 0.f;
    xt[(128 + lane) * 12 + e] = v ? e_agg[n * 64 + lane] : 0.f;
  }
  __syncthreads();
  float a[8];
#pragma unroll
  for (int e = 0; e < 8; ++e) a[e] = nb1[lane];
#pragma unroll 2
  for (int k = 0; k < 192; ++k) {
    const float wv = nw1[k * 64 + lane];
    float xk[8];
    *(f32x4*)&xk[0] = *(const f32x4*)&xt[k * 12];
    *(f32x4*)&xk[4] = *(const f32x4*)&xt[k * 12 + 4];
#pragma unroll
    for (int e = 0; e < 8; ++e) a[e] = fmaf(xk[e], wv, a[e]);
  }
#pragma unroll
  for (int e = 0; e < 8; ++e) a[e] = silu_f(a[e]);
  {
    f32x4 t0 = {a[0], a[1], a[2], a[3]};
    f32x4 t1 = {a[4], a[5], a[6], a[7]};
    *(f32x4*)&xt[lane * 12]     = t0;
    *(f32x4*)&xt[lane * 12 + 4] = t1;
  }
  float olo[8], ohi[8];
#pragma unroll
  for (int e = 0; e < 8; ++e) { olo[e] = nb2[lane]; ohi[e] = nb2[64 + lane]; }
#pragma unroll 2
  for (int k = 0; k < 64; ++k) {
    const float wl = nw2[k * HIDC + lane];
    const float wh = nw2[k * HIDC + 64 + lane];
    float hk[8];
    *(f32x4*)&hk[0] = *(const f32x4*)&xt[k * 12];
    *(f32x4*)&hk[4] = *(const f32x4*)&xt[k * 12 + 4];
#pragma unroll
    for (int e = 0; e < 8; ++e) {
      olo[e] = fmaf(hk[e], wl, olo[e]);
      ohi[e] = fmaf(hk[e], wh, ohi[e]);
    }
  }
  // fused pooling: batch is sorted -> run-compress per wave
  int curb = -1;
  float accL = 0.f, accH = 0.f, c = 0.f;
#pragma unroll
  for (int e = 0; e < 8; ++e) {
    const int n = nb + e;
    if (n < NN) {
      const int bg = batch[n];
      if (bg != curb) {
        if (curb >= 0) {
          atomicAdd(&g_sum[curb * HIDC + lane], accL);
          atomicAdd(&g_sum[curb * HIDC + 64 + lane], accH);
          if (lane == 0) atomicAdd(&g_cnt[curb], c);
        }
        curb = bg; accL = olo[e]; accH = ohi[e]; c = 1.f;
      } else {
        accL += olo[e]; accH += ohi[e]; c += 1.f;
      }
    }
  }
  if (curb >= 0) {
    atomicAdd(&g_sum[curb * HIDC + lane], accL);
    atomicAdd(&g_sum[curb * HIDC + 64 + lane], accH);
    if (lane == 0) atomicAdd(&g_cnt[curb], c);
  }
}

// ---------------- K5: relu(mean) -> relu(@w1+b1) -> @w2+b2 ----------------
__global__ __launch_bounds__(128) void k_final(
    const float* __restrict__ g_sum, const float* __restrict__ g_cnt,
    const float* __restrict__ w1, const float* __restrict__ b1,
    const float* __restrict__ w2, const float* __restrict__ b2,
    float* __restrict__ out) {
  __shared__ float sg[128];
  __shared__ float sh[128];
  const int g = blockIdx.x, j = threadIdx.x;
  const float c = fmaxf(g_cnt[g], 1.f);
  sg[j] = fmaxf(g_sum[g * HIDC + j] / c, 0.f);
  __syncthreads();
  float a = b1[j];
  for (int k = 0; k < 128; ++k) a += sg[k] * w1[k * 128 + j];
  sh[j] = fmaxf(a, 0.f);
  __syncthreads();
  if (j < OUTC) {
    float o = b2[j];
    for (int k = 0; k < 128; ++k) o += sh[k] * w2[k * OUTC + j];
    out[g * OUTC + j] = o;
  }
}

extern "C" void kernel_launch(void* const* d_in, const int* in_sizes, int n_in,
                              void* d_out, int out_size, void* d_ws, size_t ws_size,
                              hipStream_t stream) {
  const float* x     = (const float*)d_in[0];
  const float* pos   = (const float*)d_in[1];
  const float* eattr = (const float*)d_in[2];
  const int*   ei    = (const int*)d_in[3];
  const int*   batch = (const int*)d_in[4];
  const float* mlp_w[2]   = {(const float*)d_in[5],  (const float*)d_in[14]};
  const float* edge_w[2]  = {(const float*)d_in[6],  (const float*)d_in[15]};
  const float* edge_b[2]  = {(const float*)d_in[7],  (const float*)d_in[16]};
  const float* coord_w[2] = {(const float*)d_in[8],  (const float*)d_in[17]};
  const float* coord_b[2] = {(const float*)d_in[9],  (const float*)d_in[18]};
  const float* nw1[2]     = {(const float*)d_in[10], (const float*)d_in[19]};
  const float* nb1[2]     = {(const float*)d_in[11], (const float*)d_in[20]};
  const float* nw2[2]     = {(const float*)d_in[12], (const float*)d_in[21]};
  const float* nb2[2]     = {(const float*)d_in[13], (const float*)d_in[22]};
  const float* ow1 = (const float*)d_in[23];
  const float* ob1 = (const float*)d_in[24];
  const float* ow2 = (const float*)d_in[25];
  const float* ob2 = (const float*)d_in[26];
  float* out = (float*)d_out;

  char* p = (char*)d_ws;
  auto alloc = [&](size_t bytes) {
    void* r = (void*)p;
    p += (bytes + 255) & ~(size_t)255;
    return r;
  };
  float* P1     = (float*)alloc((size_t)NN * 64 * 4);
  float* P2     = (float*)alloc((size_t)NN * 64 * 4);
  float* e_agg  = (float*)alloc((size_t)NN * 64 * 4);
  float* cu     = (float*)alloc((size_t)NN * 3 * 4);
  float* x1     = (float*)alloc((size_t)NN * HIDC * 4);
  float* pos1   = (float*)alloc((size_t)NN * 3 * 4);
  float* g_sum  = (float*)alloc((size_t)GG * HIDC * 4);
  float* g_cnt  = (float*)alloc((size_t)GG * 4);
  int* cnt      = (int*)alloc((size_t)NN * 4);
  int* row_ptr  = (int*)alloc((size_t)(NN + 1) * 4);
  int* nxt      = (int*)alloc((size_t)NN * 4);
  int* sdst     = (int*)alloc((size_t)EE * 4);
  int* ssrc     = (int*)alloc((size_t)EE * 4);
  float* seattr = (float*)alloc((size_t)EE * DD * 4);

  const int nodeBlocks = (NN + 31) / 32;
  const int edgeBlocks = 1250;  // 1250 x 320 = 400000 exact

  (void)hipMemsetAsync(e_agg, 0, (size_t)NN * 64 * 4, stream);
  (void)hipMemsetAsync(cu,    0, (size_t)NN * 3 * 4, stream);
  (void)hipMemsetAsync(g_sum, 0, (size_t)GG * HIDC * 4, stream);
  (void)hipMemsetAsync(g_cnt, 0, (size_t)GG * 4, stream);
  (void)hipMemsetAsync(cnt,   0, (size_t)NN * 4, stream);

  // ---- build dst-sorted edge order + sorted eattr (shared by both layers) ----
  k_hist<<<(EE + 255) / 256, 256, 0, stream>>>(ei, cnt);
  k_scan<<<1, 1024, 0, stream>>>(cnt, row_ptr, nxt);
  k_scatter<<<(EE + 255) / 256, 256, 0, stream>>>(ei, eattr, nxt, sdst, ssrc, seattr);

  // ---- layer 0 ----
  k_precompute<<<nodeBlocks, 256, 0, stream>>>(x, mlp_w[0], P1, P2);
  k_edge<true><<<edgeBlocks, 256, 0, stream>>>(P1, P2, pos, seattr, sdst, ssrc,
      mlp_w[0], edge_w[0], edge_b[0], coord_w[0], coord_b[0], e_agg, cu);
  k_node_l0<<<nodeBlocks, 256, 0, stream>>>(x, e_agg, nw1[0], nb1[0],
      nw2[0], nb2[0], pos, cu, row_ptr, x1, pos1, mlp_w[1], P1, P2);

  // ---- layer 1 (pos output unused; e_agg pre-zeroed; P1/P2 precomputed) ----
  k_edge<false><<<edgeBlocks, 256, 0, stream>>>(P1, P2, pos1, seattr, sdst, ssrc,
      mlp_w[1], edge_w[1], edge_b[1], coord_w[1], coord_b[1], e_agg, cu);
  k_node_l1<<<nodeBlocks, 256, 0, stream>>>(x1, e_agg, nw1[1], nb1[1],
      nw2[1], nb2[1], batch, g_sum, g_cnt);

  // ---- head ----
  k_final<<<GG, 128, 0, stream>>>(g_sum, g_cnt, ow1, ob1, ow2, ob2, out);
}

// Round 10
// 515.585 us; speedup vs baseline: 1.3016x; 1.2000x over previous
//
#include <hip/hip_runtime.h>
#include <math.h>

#define NN 25000
#define EE 400000
#define FF 128
#define DD 16
#define HH 64
#define HIDC 128
#define OUTC 32
#define GG 64

typedef __attribute__((ext_vector_type(8))) short short8;
typedef __attribute__((ext_vector_type(8))) unsigned short u16x8;
typedef __attribute__((ext_vector_type(4))) float f32x4;

union S8 { short8 v; unsigned short u[8]; };
union U8 { u16x8 v; unsigned short u[8]; };

__device__ __forceinline__ float silu_f(float v) {
    return v / (1.f + __expf(-v));
}

__device__ __forceinline__ unsigned short f2bf_rne(float f) {
  unsigned u = __float_as_uint(f);
  unsigned r = u + 0x7fffu + ((u >> 16) & 1u);
  return (unsigned short)(r >> 16);
}
__device__ __forceinline__ float bfbits2f(unsigned short b) {
  return __uint_as_float(((unsigned)b) << 16);
}

// ---------------- Sort: counting sort of edges by dst ----------------
__global__ __launch_bounds__(256) void k_hist(
    const int* __restrict__ ei, int* __restrict__ cnt) {
  const int t = blockIdx.x * 256 + threadIdx.x;
  if (t < EE) atomicAdd(&cnt[ei[EE + t]], 1);
}

__global__ __launch_bounds__(1024) void k_scan(
    const int* __restrict__ cnt, int* __restrict__ row_ptr, int* __restrict__ next) {
  __shared__ int s[1024];
  const int t = threadIdx.x;
  const int base = t * 25;
  int loc[25];
  int sum = 0;
#pragma unroll
  for (int i = 0; i < 25; ++i) {
    const int n = base + i;
    loc[i] = (n < NN) ? cnt[n] : 0;
    sum += loc[i];
  }
  s[t] = sum;
  __syncthreads();
  for (int off = 1; off < 1024; off <<= 1) {
    const int v = (t >= off) ? s[t - off] : 0;
    __syncthreads();
    s[t] += v;
    __syncthreads();
  }
  int run = s[t] - sum;
#pragma unroll
  for (int i = 0; i < 25; ++i) {
    const int n = base + i;
    if (n < NN) {
      row_ptr[n] = run;
      next[n] = run;
      run += loc[i];
    }
  }
  if (t == 0) row_ptr[NN] = EE;
}

// scatter edges into dst-sorted order; also pre-gather eattr rows into sorted order
__global__ __launch_bounds__(256) void k_scatter(
    const int* __restrict__ ei, const float* __restrict__ eattr, int* __restrict__ next,
    int* __restrict__ sdst, int* __restrict__ ssrc, float* __restrict__ seattr) {
  const int t = blockIdx.x * 256 + threadIdx.x;
  if (t < EE) {
    const int d = ei[EE + t];
    const int slot = atomicAdd(&next[d], 1);
    sdst[slot] = d;
    ssrc[slot] = ei[t];
    const f32x4* s4 = (const f32x4*)&eattr[(size_t)t * DD];
    f32x4* d4 = (f32x4*)&seattr[(size_t)slot * DD];
    d4[0] = s4[0]; d4[1] = s4[1]; d4[2] = s4[2]; d4[3] = s4[3];
  }
}

// ---------------- K1: P1 = X @ W[0:128,:] (fp32), P2 = X @ W[128:256,:] (bf16) --
__global__ __launch_bounds__(256) void k_precompute(
    const float* __restrict__ X, const float* __restrict__ W,
    float* __restrict__ P1, unsigned short* __restrict__ P2h) {
  __shared__ __align__(16) float xT[4][128 * 12];
  const int w = threadIdx.x >> 6, lane = threadIdx.x & 63;
  float* xt = xT[w];
  const int nb = (blockIdx.x * 4 + w) * 8;
#pragma unroll
  for (int e = 0; e < 8; ++e) {
    const int n = nb + e;
    const bool v = n < NN;
    xt[lane * 12 + e]        = v ? X[n * FF + lane] : 0.f;
    xt[(lane + 64) * 12 + e] = v ? X[n * FF + 64 + lane] : 0.f;
  }
  __syncthreads();
  float a1[8], a2[8];
#pragma unroll
  for (int e = 0; e < 8; ++e) { a1[e] = 0.f; a2[e] = 0.f; }
#pragma unroll 4
  for (int k = 0; k < 128; ++k) {
    const float wa = W[k * 64 + lane];
    const float wb = W[(128 + k) * 64 + lane];
    float xk[8];
    *(f32x4*)&xk[0] = *(const f32x4*)&xt[k * 12];
    *(f32x4*)&xk[4] = *(const f32x4*)&xt[k * 12 + 4];
#pragma unroll
    for (int e = 0; e < 8; ++e) {
      a1[e] = fmaf(xk[e], wa, a1[e]);
      a2[e] = fmaf(xk[e], wb, a2[e]);
    }
  }
#pragma unroll
  for (int e = 0; e < 8; ++e) {
    const int n = nb + e;
    if (n < NN) {
      P1[n * 64 + lane]  = a1[e];
      P2h[n * 64 + lane] = f2bf_rne(a2[e]);
    }
  }
}

// ---------------- K2: per-edge MLP via MFMA, dst-sorted ------------------------
// (256,4): VGPR budget 128/wave -> no spill (R7-R9 showed (256,5/6) spills:
// VGPR 40/48, FETCH 350/283MB vs 157MB clean). Grid=1024, all co-resident;
// waves take 7 or 6 CONTIGUOUS 16-edge groups (424*7+3672*6=25000 exact).
// P2 is bf16 (3.2MB -> per-XCD-L2 resident) to kill the random-gather HBM cost.
template <bool COORD>
__global__ __launch_bounds__(256, 4) void k_edge(
    const float* __restrict__ P1, const unsigned short* __restrict__ P2h,
    const float* __restrict__ pos, const float* __restrict__ seattr,
    const int* __restrict__ sdst, const int* __restrict__ ssrc,
    const float* __restrict__ mlp_w,
    const float* __restrict__ edge_w, const float* __restrict__ edge_b,
    const float* __restrict__ coord_w, const float* __restrict__ coord_b,
    float* __restrict__ e_agg, float* __restrict__ cu) {
  __shared__ __align__(16) float s_hs[4][16 * 76];
  __shared__ float s_diff[4][48];
  __shared__ float s_rad[4][16];
  __shared__ float s_red[4][16];
  const int tid = threadIdx.x, w = tid >> 6, lane = tid & 63;
  const int q = lane >> 4, m = lane & 15;

  S8 wB[2][4];
#pragma unroll
  for (int kc = 0; kc < 2; ++kc)
#pragma unroll
    for (int nc = 0; nc < 4; ++nc)
#pragma unroll
      for (int j = 0; j < 8; ++j)
        wB[kc][nc].u[j] = f2bf_rne(edge_w[(kc * 32 + q * 8 + j) * 64 + nc * 16 + m]);
  S8 w3B[4];
#pragma unroll
  for (int nc = 0; nc < 4; ++nc)
#pragma unroll
    for (int j = 0; j < 8; ++j)
      w3B[nc].u[j] = (lane < 32) ? f2bf_rne(mlp_w[256 * 64 + (q * 8 + j) * 64 + nc * 16 + m])
                                 : (unsigned short)0;
  float w4r[4], cwr[4], ebr[4];
#pragma unroll
  for (int nc = 0; nc < 4; ++nc) {
    w4r[nc] = mlp_w[272 * 64 + nc * 16 + m];
    ebr[nc] = edge_b[nc * 16 + m];
    cwr[nc] = COORD ? coord_w[nc * 16 + m] : 0.f;
  }
  const float cb = COORD ? coord_b[0] : 0.f;

  // contiguous variable group assignment: 7 groups for waves 0..423, else 6
  const int wave_id = blockIdx.x * 4 + w;               // 0..4095
  const int g0 = wave_id * 6 + (wave_id < 424 ? wave_id : 424);
  const int ng = (wave_id < 424) ? 7 : 6;

  const int pe = (lane < 48) ? (lane / 3) : 0;
  const int pc = lane - (lane / 3) * 3;

  int cur_dst = -1;
  float accum = 0.f;

  for (int g = 0; g < ng; ++g) {
    const int eb = (g0 + g) * 16;          // global sorted-edge base
    const int dm = sdst[eb + m];           // lane L holds edge (L&15)'s dst
    const int sm = ssrc[eb + m];
    // P1 fp32 + P2 bf16 row gathers in A-fragment layout
    f32x4 p1a[2], p1b[2];
    U8 p2r[2];
#pragma unroll
    for (int kc = 0; kc < 2; ++kc) {
      const float* pp1 = P1 + (size_t)dm * 64 + kc * 32 + q * 8;
      p1a[kc] = *(const f32x4*)pp1;
      p1b[kc] = *(const f32x4*)(pp1 + 4);
      p2r[kc].v = *(const u16x8*)(P2h + (size_t)sm * 64 + kc * 32 + q * 8);
    }
    if (lane < 48) {
      const int de = __shfl(dm, pe, 64), se = __shfl(sm, pe, 64);
      s_diff[w][lane] = pos[de * 3 + pc] - pos[se * 3 + pc];
    }
    float ea[8] = {0.f, 0.f, 0.f, 0.f, 0.f, 0.f, 0.f, 0.f};
    if (lane < 32) {
      const float* ep = &seattr[(size_t)(eb + m) * DD + q * 8];
      *(f32x4*)&ea[0] = *(const f32x4*)ep;
      *(f32x4*)&ea[4] = *(const f32x4*)(ep + 4);
    }
    S8 eaA;
#pragma unroll
    for (int j = 0; j < 8; ++j) eaA.u[j] = f2bf_rne(ea[j]);
    if (lane < 16) {
      const float d0 = s_diff[w][lane * 3 + 0];
      const float d1 = s_diff[w][lane * 3 + 1];
      const float d2 = s_diff[w][lane * 3 + 2];
      s_rad[w][lane] = fmaf(d0, d0, fmaf(d1, d1, d2 * d2));
    }
    float radr[4];
#pragma unroll
    for (int r = 0; r < 4; ++r) radr[r] = s_rad[w][q * 4 + r];
    f32x4 c3[4];
#pragma unroll
    for (int nc = 0; nc < 4; ++nc) {
      f32x4 z = {0.f, 0.f, 0.f, 0.f};
      c3[nc] = __builtin_amdgcn_mfma_f32_16x16x32_bf16(eaA.v, w3B[nc].v, z, 0, 0, 0);
    }
#pragma unroll
    for (int nc = 0; nc < 4; ++nc)
#pragma unroll
      for (int r = 0; r < 4; ++r)
        s_hs[w][(q * 4 + r) * 76 + nc * 16 + m] = fmaf(radr[r], w4r[nc], c3[nc][r]);
    S8 ahi[2], alo[2];
#pragma unroll
    for (int kc = 0; kc < 2; ++kc) {
      const float* hp = &s_hs[w][m * 76 + kc * 32 + q * 8];
      f32x4 h0 = *(const f32x4*)hp;
      f32x4 h1 = *(const f32x4*)(hp + 4);
      h0 = h0 + p1a[kc];
      h1 = h1 + p1b[kc];
      float hv[8];
      *(f32x4*)&hv[0] = h0;
      *(f32x4*)&hv[4] = h1;
#pragma unroll
      for (int j = 0; j < 8; ++j) {
        const float h = silu_f(hv[j] + bfbits2f(p2r[kc].u[j]));
        const unsigned short hb = (unsigned short)(__float_as_uint(h) >> 16);
        ahi[kc].u[j] = hb;
        alo[kc].u[j] = f2bf_rne(h - bfbits2f(hb));
      }
    }
    f32x4 o[4];
#pragma unroll
    for (int nc = 0; nc < 4; ++nc) {
      f32x4 bi = {ebr[nc], ebr[nc], ebr[nc], ebr[nc]};
      o[nc] = bi;
    }
#pragma unroll
    for (int kc = 0; kc < 2; ++kc)
#pragma unroll
      for (int nc = 0; nc < 4; ++nc) {
        o[nc] = __builtin_amdgcn_mfma_f32_16x16x32_bf16(ahi[kc].v, wB[kc][nc].v, o[nc], 0, 0, 0);
        o[nc] = __builtin_amdgcn_mfma_f32_16x16x32_bf16(alo[kc].v, wB[kc][nc].v, o[nc], 0, 0, 0);
      }
#pragma unroll
    for (int nc = 0; nc < 4; ++nc)
#pragma unroll
      for (int r = 0; r < 4; ++r) o[nc][r] = silu_f(o[nc][r]);
    if (COORD) {
#pragma unroll
      for (int r = 0; r < 4; ++r) {
        float v = o[0][r] * cwr[0] + o[1][r] * cwr[1] + o[2][r] * cwr[2] + o[3][r] * cwr[3];
        v += __shfl_xor(v, 1, 64);
        v += __shfl_xor(v, 2, 64);
        v += __shfl_xor(v, 4, 64);
        v += __shfl_xor(v, 8, 64);
        if (m == 0) s_red[w][q * 4 + r] = v;
      }
    }
#pragma unroll
    for (int nc = 0; nc < 4; ++nc)
#pragma unroll
      for (int r = 0; r < 4; ++r)
        s_hs[w][(q * 4 + r) * 76 + nc * 16 + m] = o[nc][r];
    for (int e = 0; e < 16; ++e) {
      const int dv = __shfl(dm, e, 64);    // wave-uniform
      const float v = s_hs[w][e * 76 + lane];
      if (dv == cur_dst) {
        accum += v;
      } else {
        if (cur_dst >= 0) atomicAdd(&e_agg[(size_t)cur_dst * 64 + lane], accum);
        cur_dst = dv;
        accum = v;
      }
    }
    if (COORD) {
      if (lane < 48) {
        const float s = silu_f(s_red[w][pe] + cb);
        atomicAdd(&cu[(size_t)__shfl(dm, pe, 64) * 3 + pc], s_diff[w][lane] * s);
      }
    }
  }
  if (cur_dst >= 0) atomicAdd(&e_agg[(size_t)cur_dst * 64 + lane], accum);
}

// ------- K3a: layer-0 node MLP + pos update + e_agg rezero + layer-1 precompute -
__global__ __launch_bounds__(256) void k_node_l0(
    const float* __restrict__ x_in, float* __restrict__ e_agg,
    const float* __restrict__ nw1, const float* __restrict__ nb1,
    const float* __restrict__ nw2, const float* __restrict__ nb2,
    const float* __restrict__ pos_in, const float* __restrict__ cu,
    const int* __restrict__ row_ptr,
    float* __restrict__ x_out, float* __restrict__ pos_out,
    const float* __restrict__ Wn, float* __restrict__ P1,
    unsigned short* __restrict__ P2h) {
  __shared__ __align__(16) float xT[4][192 * 12];
  const int w = threadIdx.x >> 6, lane = threadIdx.x & 63;
  float* xt = xT[w];
  const int nb = (blockIdx.x * 4 + w) * 8;
#pragma unroll
  for (int e = 0; e < 8; ++e) {
    const int n = nb + e;
    const bool v = n < NN;
    xt[lane * 12 + e]         = v ? x_in[n * HIDC + lane] : 0.f;
    xt[(64 + lane) * 12 + e]  = v ? x_in[n * HIDC + 64 + lane] : 0.f;
    xt[(128 + lane) * 12 + e] = v ? e_agg[n * 64 + lane] : 0.f;
    if (v) e_agg[n * 64 + lane] = 0.f;
  }
  __syncthreads();
  float a[8];
#pragma unroll
  for (int e = 0; e < 8; ++e) a[e] = nb1[lane];
#pragma unroll 2
  for (int k = 0; k < 192; ++k) {
    const float wv = nw1[k * 64 + lane];
    float xk[8];
    *(f32x4*)&xk[0] = *(const f32x4*)&xt[k * 12];
    *(f32x4*)&xk[4] = *(const f32x4*)&xt[k * 12 + 4];
#pragma unroll
    for (int e = 0; e < 8; ++e) a[e] = fmaf(xk[e], wv, a[e]);
  }
#pragma unroll
  for (int e = 0; e < 8; ++e) a[e] = silu_f(a[e]);
  {
    f32x4 t0 = {a[0], a[1], a[2], a[3]};
    f32x4 t1 = {a[4], a[5], a[6], a[7]};
    *(f32x4*)&xt[lane * 12]     = t0;
    *(f32x4*)&xt[lane * 12 + 4] = t1;
  }
  float olo[8], ohi[8];
#pragma unroll
  for (int e = 0; e < 8; ++e) { olo[e] = nb2[lane]; ohi[e] = nb2[64 + lane]; }
#pragma unroll 2
  for (int k = 0; k < 64; ++k) {
    const float wl = nw2[k * HIDC + lane];
    const float wh = nw2[k * HIDC + 64 + lane];
    float hk[8];
    *(f32x4*)&hk[0] = *(const f32x4*)&xt[k * 12];
    *(f32x4*)&hk[4] = *(const f32x4*)&xt[k * 12 + 4];
#pragma unroll
    for (int e = 0; e < 8; ++e) {
      olo[e] = fmaf(hk[e], wl, olo[e]);
      ohi[e] = fmaf(hk[e], wh, ohi[e]);
    }
  }
#pragma unroll
  for (int e = 0; e < 8; ++e) {
    const int n = nb + e;
    if (n < NN) {
      x_out[n * HIDC + lane]      = olo[e];
      x_out[n * HIDC + 64 + lane] = ohi[e];
    }
  }
#pragma unroll
  for (int e = 0; e < 8; ++e) {
    const int n = nb + e;
    if (n < NN && lane < 3) {
      const float dg = fmaxf((float)(row_ptr[n + 1] - row_ptr[n]), 1.f);
      pos_out[n * 3 + lane] = pos_in[n * 3 + lane] + cu[n * 3 + lane] / dg;
    }
  }
  // ---- fused layer-1 precompute: stage x1 transposed, P = x1 @ Wn ----
  {
    f32x4 t0 = {olo[0], olo[1], olo[2], olo[3]};
    f32x4 t1 = {olo[4], olo[5], olo[6], olo[7]};
    *(f32x4*)&xt[lane * 12]     = t0;
    *(f32x4*)&xt[lane * 12 + 4] = t1;
    f32x4 t2 = {ohi[0], ohi[1], ohi[2], ohi[3]};
    f32x4 t3 = {ohi[4], ohi[5], ohi[6], ohi[7]};
    *(f32x4*)&xt[(64 + lane) * 12]     = t2;
    *(f32x4*)&xt[(64 + lane) * 12 + 4] = t3;
  }
  float a1[8], a2[8];
#pragma unroll
  for (int e = 0; e < 8; ++e) { a1[e] = 0.f; a2[e] = 0.f; }
#pragma unroll 4
  for (int k = 0; k < 128; ++k) {
    const float wa = Wn[k * 64 + lane];
    const float wb2 = Wn[(128 + k) * 64 + lane];
    float xk[8];
    *(f32x4*)&xk[0] = *(const f32x4*)&xt[k * 12];
    *(f32x4*)&xk[4] = *(const f32x4*)&xt[k * 12 + 4];
#pragma unroll
    for (int e = 0; e < 8; ++e) {
      a1[e] = fmaf(xk[e], wa, a1[e]);
      a2[e] = fmaf(xk[e], wb2, a2[e]);
    }
  }
#pragma unroll
  for (int e = 0; e < 8; ++e) {
    const int n = nb + e;
    if (n < NN) {
      P1[n * 64 + lane]  = a1[e];
      P2h[n * 64 + lane] = f2bf_rne(a2[e]);
    }
  }
}

// ------- K3b: layer-1 node MLP + fused batch mean-pool partials ----------------
__global__ __launch_bounds__(256) void k_node_l1(
    const float* __restrict__ x_in, const float* __restrict__ e_agg,
    const float* __restrict__ nw1, const float* __restrict__ nb1,
    const float* __restrict__ nw2, const float* __restrict__ nb2,
    const int* __restrict__ batch,
    float* __restrict__ g_sum, float* __restrict__ g_cnt) {
  __shared__ __align__(16) float xT[4][192 * 12];
  const int w = threadIdx.x >> 6, lane = threadIdx.x & 63;
  float* xt = xT[w];
  const int nb = (blockIdx.x * 4 + w) * 8;
#pragma unroll
  for (int e = 0; e < 8; ++e) {
    const int n = nb + e;
    const bool v = n < NN;
    xt[lane * 12 + e]         = v ? x_in[n * HIDC + lane] : 0.f;
    xt[(64 + lane) * 12 + e]  = v ? x_in[n * HIDC + 64 + lane] : 0.f;
    xt[(128 + lane) * 12 + e] = v ? e_agg[n * 64 + lane] : 0.f;
  }
  __syncthreads();
  float a[8];
#pragma unroll
  for (int e = 0; e < 8; ++e) a[e] = nb1[lane];
#pragma unroll 2
  for (int k = 0; k < 192; ++k) {
    const float wv = nw1[k * 64 + lane];
    float xk[8];
    *(f32x4*)&xk[0] = *(const f32x4*)&xt[k * 12];
    *(f32x4*)&xk[4] = *(const f32x4*)&xt[k * 12 + 4];
#pragma unroll
    for (int e = 0; e < 8; ++e) a[e] = fmaf(xk[e], wv, a[e]);
  }
#pragma unroll
  for (int e = 0; e < 8; ++e) a[e] = silu_f(a[e]);
  {
    f32x4 t0 = {a[0], a[1], a[2], a[3]};
    f32x4 t1 = {a[4], a[5], a[6], a[7]};
    *(f32x4*)&xt[lane * 12]     = t0;
    *(f32x4*)&xt[lane * 12 + 4] = t1;
  }
  float olo[8], ohi[8];
#pragma unroll
  for (int e = 0; e < 8; ++e) { olo[e] = nb2[lane]; ohi[e] = nb2[64 + lane]; }
#pragma unroll 2
  for (int k = 0; k < 64; ++k) {
    const float wl = nw2[k * HIDC + lane];
    const float wh = nw2[k * HIDC + 64 + lane];
    float hk[8];
    *(f32x4*)&hk[0] = *(const f32x4*)&xt[k * 12];
    *(f32x4*)&hk[4] = *(const f32x4*)&xt[k * 12 + 4];
#pragma unroll
    for (int e = 0; e < 8; ++e) {
      olo[e] = fmaf(hk[e], wl, olo[e]);
      ohi[e] = fmaf(hk[e], wh, ohi[e]);
    }
  }
  // fused pooling: batch is sorted -> run-compress per wave
  int curb = -1;
  float accL = 0.f, accH = 0.f, c = 0.f;
#pragma unroll
  for (int e = 0; e < 8; ++e) {
    const int n = nb + e;
    if (n < NN) {
      const int bg = batch[n];
      if (bg != curb) {
        if (curb >= 0) {
          atomicAdd(&g_sum[curb * HIDC + lane], accL);
          atomicAdd(&g_sum[curb * HIDC + 64 + lane], accH);
          if (lane == 0) atomicAdd(&g_cnt[curb], c);
        }
        curb = bg; accL = olo[e]; accH = ohi[e]; c = 1.f;
      } else {
        accL += olo[e]; accH += ohi[e]; c += 1.f;
      }
    }
  }
  if (curb >= 0) {
    atomicAdd(&g_sum[curb * HIDC + lane], accL);
    atomicAdd(&g_sum[curb * HIDC + 64 + lane], accH);
    if (lane == 0) atomicAdd(&g_cnt[curb], c);
  }
}

// ---------------- K5: relu(mean) -> relu(@w1+b1) -> @w2+b2 ----------------
__global__ __launch_bounds__(128) void k_final(
    const float* __restrict__ g_sum, const float* __restrict__ g_cnt,
    const float* __restrict__ w1, const float* __restrict__ b1,
    const float* __restrict__ w2, const float* __restrict__ b2,
    float* __restrict__ out) {
  __shared__ float sg[128];
  __shared__ float sh[128];
  const int g = blockIdx.x, j = threadIdx.x;
  const float c = fmaxf(g_cnt[g], 1.f);
  sg[j] = fmaxf(g_sum[g * HIDC + j] / c, 0.f);
  __syncthreads();
  float a = b1[j];
  for (int k = 0; k < 128; ++k) a += sg[k] * w1[k * 128 + j];
  sh[j] = fmaxf(a, 0.f);
  __syncthreads();
  if (j < OUTC) {
    float o = b2[j];
    for (int k = 0; k < 128; ++k) o += sh[k] * w2[k * OUTC + j];
    out[g * OUTC + j] = o;
  }
}

extern "C" void kernel_launch(void* const* d_in, const int* in_sizes, int n_in,
                              void* d_out, int out_size, void* d_ws, size_t ws_size,
                              hipStream_t stream) {
  const float* x     = (const float*)d_in[0];
  const float* pos   = (const float*)d_in[1];
  const float* eattr = (const float*)d_in[2];
  const int*   ei    = (const int*)d_in[3];
  const int*   batch = (const int*)d_in[4];
  const float* mlp_w[2]   = {(const float*)d_in[5],  (const float*)d_in[14]};
  const float* edge_w[2]  = {(const float*)d_in[6],  (const float*)d_in[15]};
  const float* edge_b[2]  = {(const float*)d_in[7],  (const float*)d_in[16]};
  const float* coord_w[2] = {(const float*)d_in[8],  (const float*)d_in[17]};
  const float* coord_b[2] = {(const float*)d_in[9],  (const float*)d_in[18]};
  const float* nw1[2]     = {(const float*)d_in[10], (const float*)d_in[19]};
  const float* nb1[2]     = {(const float*)d_in[11], (const float*)d_in[20]};
  const float* nw2[2]     = {(const float*)d_in[12], (const float*)d_in[21]};
  const float* nb2[2]     = {(const float*)d_in[13], (const float*)d_in[22]};
  const float* ow1 = (const float*)d_in[23];
  const float* ob1 = (const float*)d_in[24];
  const float* ow2 = (const float*)d_in[25];
  const float* ob2 = (const float*)d_in[26];
  float* out = (float*)d_out;

  char* p = (char*)d_ws;
  auto alloc = [&](size_t bytes) {
    void* r = (void*)p;
    p += (bytes + 255) & ~(size_t)255;
    return r;
  };
  float* P1            = (float*)alloc((size_t)NN * 64 * 4);
  unsigned short* P2h  = (unsigned short*)alloc((size_t)NN * 64 * 2);
  float* e_agg         = (float*)alloc((size_t)NN * 64 * 4);
  float* cu            = (float*)alloc((size_t)NN * 3 * 4);
  float* x1            = (float*)alloc((size_t)NN * HIDC * 4);
  float* pos1          = (float*)alloc((size_t)NN * 3 * 4);
  float* g_sum         = (float*)alloc((size_t)GG * HIDC * 4);
  float* g_cnt         = (float*)alloc((size_t)GG * 4);
  int* cnt             = (int*)alloc((size_t)NN * 4);
  int* row_ptr         = (int*)alloc((size_t)(NN + 1) * 4);
  int* nxt             = (int*)alloc((size_t)NN * 4);
  int* sdst            = (int*)alloc((size_t)EE * 4);
  int* ssrc            = (int*)alloc((size_t)EE * 4);
  float* seattr        = (float*)alloc((size_t)EE * DD * 4);

  const int nodeBlocks = (NN + 31) / 32;
  const int edgeBlocks = 1024;  // 4096 waves x (7|6) groups x 16 = 400000 exact

  (void)hipMemsetAsync(e_agg, 0, (size_t)NN * 64 * 4, stream);
  (void)hipMemsetAsync(cu,    0, (size_t)NN * 3 * 4, stream);
  (void)hipMemsetAsync(g_sum, 0, (size_t)GG * HIDC * 4, stream);
  (void)hipMemsetAsync(g_cnt, 0, (size_t)GG * 4, stream);
  (void)hipMemsetAsync(cnt,   0, (size_t)NN * 4, stream);

  // ---- build dst-sorted edge order + sorted eattr (shared by both layers) ----
  k_hist<<<(EE + 255) / 256, 256, 0, stream>>>(ei, cnt);
  k_scan<<<1, 1024, 0, stream>>>(cnt, row_ptr, nxt);
  k_scatter<<<(EE + 255) / 256, 256, 0, stream>>>(ei, eattr, nxt, sdst, ssrc, seattr);

  // ---- layer 0 ----
  k_precompute<<<nodeBlocks, 256, 0, stream>>>(x, mlp_w[0], P1, P2h);
  k_edge<true><<<edgeBlocks, 256, 0, stream>>>(P1, P2h, pos, seattr, sdst, ssrc,
      mlp_w[0], edge_w[0], edge_b[0], coord_w[0], coord_b[0], e_agg, cu);
  k_node_l0<<<nodeBlocks, 256, 0, stream>>>(x, e_agg, nw1[0], nb1[0],
      nw2[0], nb2[0], pos, cu, row_ptr, x1, pos1, mlp_w[1], P1, P2h);

  // ---- layer 1 (pos output unused; e_agg pre-zeroed; P1/P2 precomputed) ----
  k_edge<false><<<edgeBlocks, 256, 0, stream>>>(P1, P2h, pos1, seattr, sdst, ssrc,
      mlp_w[1], edge_w[1], edge_b[1], coord_w[1], coord_b[1], e_agg, cu);
  k_node_l1<<<nodeBlocks, 256, 0, stream>>>(x1, e_agg, nw1[1], nb1[1],
      nw2[1], nb2[1], batch, g_sum, g_cnt);

  // ---- head ----
  k_final<<<GG, 128, 0, stream>>>(g_sum, g_cnt, ow1, ob1, ow2, ob2, out);
}

// Round 11
// 507.944 us; speedup vs baseline: 1.3211x; 1.0150x over previous
//
#include <hip/hip_runtime.h>
#include <math.h>

#define NN 25000
#define EE 400000
#define FF 128
#define DD 16
#define HH 64
#define HIDC 128
#define OUTC 32
#define GG 64
#define NODEBLK 782   // ceil(25000/32)
#define SCATBLK 1563  // ceil(400000/256)

typedef __attribute__((ext_vector_type(8))) short short8;
typedef __attribute__((ext_vector_type(8))) unsigned short u16x8;
typedef __attribute__((ext_vector_type(4))) float f32x4;

union S8 { short8 v; unsigned short u[8]; };
union U8 { u16x8 v; unsigned short u[8]; };

__device__ __forceinline__ float silu_f(float v) {
    return v / (1.f + __expf(-v));
}

__device__ __forceinline__ unsigned short f2bf_rne(float f) {
  unsigned u = __float_as_uint(f);
  unsigned r = u + 0x7fffu + ((u >> 16) & 1u);
  return (unsigned short)(r >> 16);
}
__device__ __forceinline__ float bfbits2f(unsigned short b) {
  return __uint_as_float(((unsigned)b) << 16);
}

// ---------------- Sort step 1: histogram of dst ----------------
__global__ __launch_bounds__(256) void k_hist(
    const int* __restrict__ ei, int* __restrict__ cnt) {
  const int t = blockIdx.x * 256 + threadIdx.x;
  if (t < EE) atomicAdd(&cnt[ei[EE + t]], 1);
}

// ---------------- Sort step 2: exclusive scan ----------------
__global__ __launch_bounds__(1024) void k_scan(
    const int* __restrict__ cnt, int* __restrict__ row_ptr, int* __restrict__ next) {
  __shared__ int s[1024];
  const int t = threadIdx.x;
  const int base = t * 25;
  int loc[25];
  int sum = 0;
#pragma unroll
  for (int i = 0; i < 25; ++i) {
    const int n = base + i;
    loc[i] = (n < NN) ? cnt[n] : 0;
    sum += loc[i];
  }
  s[t] = sum;
  __syncthreads();
  for (int off = 1; off < 1024; off <<= 1) {
    const int v = (t >= off) ? s[t - off] : 0;
    __syncthreads();
    s[t] += v;
    __syncthreads();
  }
  int run = s[t] - sum;
#pragma unroll
  for (int i = 0; i < 25; ++i) {
    const int n = base + i;
    if (n < NN) {
      row_ptr[n] = run;
      next[n] = run;
      run += loc[i];
    }
  }
  if (t == 0) row_ptr[NN] = EE;
}

// ------- Fused: scatter (index-only, no eattr copy) + layer-0 P precompute -----
// blocks [0, NODEBLK): P1 = X@W[0:128] (fp32), P2h = X@W[128:256] (bf16)
// blocks [NODEBLK, NODEBLK+SCATBLK): dst-sorted index build (4B random writes only)
__global__ __launch_bounds__(256) void k_sp(
    const int* __restrict__ ei, int* __restrict__ next,
    int* __restrict__ sdst, int* __restrict__ ssrc, int* __restrict__ seid,
    const float* __restrict__ X, const float* __restrict__ W,
    float* __restrict__ P1, unsigned short* __restrict__ P2h) {
  __shared__ __align__(16) float xT[4][128 * 12];
  if (blockIdx.x >= NODEBLK) {
    const int t = (blockIdx.x - NODEBLK) * 256 + threadIdx.x;
    if (t < EE) {
      const int d = ei[EE + t];
      const int slot = atomicAdd(&next[d], 1);
      sdst[slot] = d;
      ssrc[slot] = ei[t];
      seid[slot] = t;
    }
    return;
  }
  const int w = threadIdx.x >> 6, lane = threadIdx.x & 63;
  float* xt = xT[w];
  const int nb = (blockIdx.x * 4 + w) * 8;
#pragma unroll
  for (int e = 0; e < 8; ++e) {
    const int n = nb + e;
    const bool v = n < NN;
    xt[lane * 12 + e]        = v ? X[n * FF + lane] : 0.f;
    xt[(lane + 64) * 12 + e] = v ? X[n * FF + 64 + lane] : 0.f;
  }
  __syncthreads();
  float a1[8], a2[8];
#pragma unroll
  for (int e = 0; e < 8; ++e) { a1[e] = 0.f; a2[e] = 0.f; }
#pragma unroll 4
  for (int k = 0; k < 128; ++k) {
    const float wa = W[k * 64 + lane];
    const float wb = W[(128 + k) * 64 + lane];
    float xk[8];
    *(f32x4*)&xk[0] = *(const f32x4*)&xt[k * 12];
    *(f32x4*)&xk[4] = *(const f32x4*)&xt[k * 12 + 4];
#pragma unroll
    for (int e = 0; e < 8; ++e) {
      a1[e] = fmaf(xk[e], wa, a1[e]);
      a2[e] = fmaf(xk[e], wb, a2[e]);
    }
  }
#pragma unroll
  for (int e = 0; e < 8; ++e) {
    const int n = nb + e;
    if (n < NN) {
      P1[n * 64 + lane]  = a1[e];
      P2h[n * 64 + lane] = f2bf_rne(a2[e]);
    }
  }
}

// ---------------- K2: per-edge MLP via MFMA, dst-sorted ------------------------
// (256,4): combined VGPR+AGPR budget 128/wave -> no spill (R7-R10 evidence).
// Grid=1024, all co-resident; waves take 7|6 contiguous 16-edge groups.
// GATHER (layer 0): ea loaded via seid from original eattr (random READS, no
// RMW) and stored to seattr sequentially; layer 1 reads seattr sequentially.
template <bool COORD, bool GATHER>
__global__ __launch_bounds__(256, 4) void k_edge(
    const float* __restrict__ P1, const unsigned short* __restrict__ P2h,
    const float* __restrict__ pos, const float* __restrict__ eattr,
    float* __restrict__ seattr, const int* __restrict__ seid,
    const int* __restrict__ sdst, const int* __restrict__ ssrc,
    const float* __restrict__ mlp_w,
    const float* __restrict__ edge_w, const float* __restrict__ edge_b,
    const float* __restrict__ coord_w, const float* __restrict__ coord_b,
    float* __restrict__ e_agg, float* __restrict__ cu) {
  __shared__ __align__(16) float s_hs[4][16 * 76];
  __shared__ float s_diff[4][48];
  __shared__ float s_rad[4][16];
  __shared__ float s_red[4][16];
  const int tid = threadIdx.x, w = tid >> 6, lane = tid & 63;
  const int q = lane >> 4, m = lane & 15;

  S8 wB[2][4];
#pragma unroll
  for (int kc = 0; kc < 2; ++kc)
#pragma unroll
    for (int nc = 0; nc < 4; ++nc)
#pragma unroll
      for (int j = 0; j < 8; ++j)
        wB[kc][nc].u[j] = f2bf_rne(edge_w[(kc * 32 + q * 8 + j) * 64 + nc * 16 + m]);
  S8 w3B[4];
#pragma unroll
  for (int nc = 0; nc < 4; ++nc)
#pragma unroll
    for (int j = 0; j < 8; ++j)
      w3B[nc].u[j] = (lane < 32) ? f2bf_rne(mlp_w[256 * 64 + (q * 8 + j) * 64 + nc * 16 + m])
                                 : (unsigned short)0;
  float w4r[4], cwr[4], ebr[4];
#pragma unroll
  for (int nc = 0; nc < 4; ++nc) {
    w4r[nc] = mlp_w[272 * 64 + nc * 16 + m];
    ebr[nc] = edge_b[nc * 16 + m];
    cwr[nc] = COORD ? coord_w[nc * 16 + m] : 0.f;
  }
  const float cb = COORD ? coord_b[0] : 0.f;

  const int wave_id = blockIdx.x * 4 + w;               // 0..4095
  const int g0 = wave_id * 6 + (wave_id < 424 ? wave_id : 424);
  const int ng = (wave_id < 424) ? 7 : 6;

  const int pe = (lane < 48) ? (lane / 3) : 0;
  const int pc = lane - (lane / 3) * 3;

  int cur_dst = -1;
  float accum = 0.f;

  for (int g = 0; g < ng; ++g) {
    const int eb = (g0 + g) * 16;
    const int dm = sdst[eb + m];
    const int sm = ssrc[eb + m];
    f32x4 p1a[2], p1b[2];
    U8 p2r[2];
#pragma unroll
    for (int kc = 0; kc < 2; ++kc) {
      const float* pp1 = P1 + (size_t)dm * 64 + kc * 32 + q * 8;
      p1a[kc] = *(const f32x4*)pp1;
      p1b[kc] = *(const f32x4*)(pp1 + 4);
      p2r[kc].v = *(const u16x8*)(P2h + (size_t)sm * 64 + kc * 32 + q * 8);
    }
    if (lane < 48) {
      const int de = __shfl(dm, pe, 64), se = __shfl(sm, pe, 64);
      s_diff[w][lane] = pos[de * 3 + pc] - pos[se * 3 + pc];
    }
    f32x4 ea0 = {0.f, 0.f, 0.f, 0.f}, ea1 = {0.f, 0.f, 0.f, 0.f};
    if (lane < 32) {
      if (GATHER) {
        const int eid = seid[eb + m];
        const float* ep = &eattr[(size_t)eid * DD + q * 8];
        ea0 = *(const f32x4*)ep;
        ea1 = *(const f32x4*)(ep + 4);
        // write sorted copy for layer 1 (sequential stores)
        float* sp = &seattr[(size_t)(eb + m) * DD + q * 8];
        *(f32x4*)sp = ea0;
        *(f32x4*)(sp + 4) = ea1;
      } else {
        const float* ep = &seattr[(size_t)(eb + m) * DD + q * 8];
        ea0 = *(const f32x4*)ep;
        ea1 = *(const f32x4*)(ep + 4);
      }
    }
    S8 eaA;
#pragma unroll
    for (int j = 0; j < 4; ++j) {
      eaA.u[j]     = f2bf_rne(ea0[j]);
      eaA.u[4 + j] = f2bf_rne(ea1[j]);
    }
    if (lane < 16) {
      const float d0 = s_diff[w][lane * 3 + 0];
      const float d1 = s_diff[w][lane * 3 + 1];
      const float d2 = s_diff[w][lane * 3 + 2];
      s_rad[w][lane] = fmaf(d0, d0, fmaf(d1, d1, d2 * d2));
    }
    float radr[4];
#pragma unroll
    for (int r = 0; r < 4; ++r) radr[r] = s_rad[w][q * 4 + r];
    f32x4 c3[4];
#pragma unroll
    for (int nc = 0; nc < 4; ++nc) {
      f32x4 z = {0.f, 0.f, 0.f, 0.f};
      c3[nc] = __builtin_amdgcn_mfma_f32_16x16x32_bf16(eaA.v, w3B[nc].v, z, 0, 0, 0);
    }
#pragma unroll
    for (int nc = 0; nc < 4; ++nc)
#pragma unroll
      for (int r = 0; r < 4; ++r)
        s_hs[w][(q * 4 + r) * 76 + nc * 16 + m] = fmaf(radr[r], w4r[nc], c3[nc][r]);
    S8 ahi[2], alo[2];
#pragma unroll
    for (int kc = 0; kc < 2; ++kc) {
      const float* hp = &s_hs[w][m * 76 + kc * 32 + q * 8];
      f32x4 h0 = *(const f32x4*)hp;
      f32x4 h1 = *(const f32x4*)(hp + 4);
      h0 = h0 + p1a[kc];
      h1 = h1 + p1b[kc];
      float hv[8];
      *(f32x4*)&hv[0] = h0;
      *(f32x4*)&hv[4] = h1;
#pragma unroll
      for (int j = 0; j < 8; ++j) {
        const float h = silu_f(hv[j] + bfbits2f(p2r[kc].u[j]));
        const unsigned short hb = (unsigned short)(__float_as_uint(h) >> 16);
        ahi[kc].u[j] = hb;
        alo[kc].u[j] = f2bf_rne(h - bfbits2f(hb));
      }
    }
    f32x4 o[4];
#pragma unroll
    for (int nc = 0; nc < 4; ++nc) {
      f32x4 bi = {ebr[nc], ebr[nc], ebr[nc], ebr[nc]};
      o[nc] = bi;
    }
#pragma unroll
    for (int kc = 0; kc < 2; ++kc)
#pragma unroll
      for (int nc = 0; nc < 4; ++nc) {
        o[nc] = __builtin_amdgcn_mfma_f32_16x16x32_bf16(ahi[kc].v, wB[kc][nc].v, o[nc], 0, 0, 0);
        o[nc] = __builtin_amdgcn_mfma_f32_16x16x32_bf16(alo[kc].v, wB[kc][nc].v, o[nc], 0, 0, 0);
      }
#pragma unroll
    for (int nc = 0; nc < 4; ++nc)
#pragma unroll
      for (int r = 0; r < 4; ++r) o[nc][r] = silu_f(o[nc][r]);
    if (COORD) {
#pragma unroll
      for (int r = 0; r < 4; ++r) {
        float v = o[0][r] * cwr[0] + o[1][r] * cwr[1] + o[2][r] * cwr[2] + o[3][r] * cwr[3];
        v += __shfl_xor(v, 1, 64);
        v += __shfl_xor(v, 2, 64);
        v += __shfl_xor(v, 4, 64);
        v += __shfl_xor(v, 8, 64);
        if (m == 0) s_red[w][q * 4 + r] = v;
      }
    }
#pragma unroll
    for (int nc = 0; nc < 4; ++nc)
#pragma unroll
      for (int r = 0; r < 4; ++r)
        s_hs[w][(q * 4 + r) * 76 + nc * 16 + m] = o[nc][r];
    for (int e = 0; e < 16; ++e) {
      const int dv = __shfl(dm, e, 64);
      const float v = s_hs[w][e * 76 + lane];
      if (dv == cur_dst) {
        accum += v;
      } else {
        if (cur_dst >= 0) atomicAdd(&e_agg[(size_t)cur_dst * 64 + lane], accum);
        cur_dst = dv;
        accum = v;
      }
    }
    if (COORD) {
      if (lane < 48) {
        const float s = silu_f(s_red[w][pe] + cb);
        atomicAdd(&cu[(size_t)__shfl(dm, pe, 64) * 3 + pc], s_diff[w][lane] * s);
      }
    }
  }
  if (cur_dst >= 0) atomicAdd(&e_agg[(size_t)cur_dst * 64 + lane], accum);
}

// ------- K3a: layer-0 node MLP + pos update + e_agg rezero + layer-1 precompute -
__global__ __launch_bounds__(256) void k_node_l0(
    const float* __restrict__ x_in, float* __restrict__ e_agg,
    const float* __restrict__ nw1, const float* __restrict__ nb1,
    const float* __restrict__ nw2, const float* __restrict__ nb2,
    const float* __restrict__ pos_in, const float* __restrict__ cu,
    const int* __restrict__ row_ptr,
    float* __restrict__ x_out, float* __restrict__ pos_out,
    const float* __restrict__ Wn, float* __restrict__ P1,
    unsigned short* __restrict__ P2h) {
  __shared__ __align__(16) float xT[4][192 * 12];
  const int w = threadIdx.x >> 6, lane = threadIdx.x & 63;
  float* xt = xT[w];
  const int nb = (blockIdx.x * 4 + w) * 8;
#pragma unroll
  for (int e = 0; e < 8; ++e) {
    const int n = nb + e;
    const bool v = n < NN;
    xt[lane * 12 + e]         = v ? x_in[n * HIDC + lane] : 0.f;
    xt[(64 + lane) * 12 + e]  = v ? x_in[n * HIDC + 64 + lane] : 0.f;
    xt[(128 + lane) * 12 + e] = v ? e_agg[n * 64 + lane] : 0.f;
    if (v) e_agg[n * 64 + lane] = 0.f;
  }
  __syncthreads();
  float a[8];
#pragma unroll
  for (int e = 0; e < 8; ++e) a[e] = nb1[lane];
#pragma unroll 2
  for (int k = 0; k < 192; ++k) {
    const float wv = nw1[k * 64 + lane];
    float xk[8];
    *(f32x4*)&xk[0] = *(const f32x4*)&xt[k * 12];
    *(f32x4*)&xk[4] = *(const f32x4*)&xt[k * 12 + 4];
#pragma unroll
    for (int e = 0; e < 8; ++e) a[e] = fmaf(xk[e], wv, a[e]);
  }
#pragma unroll
  for (int e = 0; e < 8; ++e) a[e] = silu_f(a[e]);
  {
    f32x4 t0 = {a[0], a[1], a[2], a[3]};
    f32x4 t1 = {a[4], a[5], a[6], a[7]};
    *(f32x4*)&xt[lane * 12]     = t0;
    *(f32x4*)&xt[lane * 12 + 4] = t1;
  }
  float olo[8], ohi[8];
#pragma unroll
  for (int e = 0; e < 8; ++e) { olo[e] = nb2[lane]; ohi[e] = nb2[64 + lane]; }
#pragma unroll 2
  for (int k = 0; k < 64; ++k) {
    const float wl = nw2[k * HIDC + lane];
    const float wh = nw2[k * HIDC + 64 + lane];
    float hk[8];
    *(f32x4*)&hk[0] = *(const f32x4*)&xt[k * 12];
    *(f32x4*)&hk[4] = *(const f32x4*)&xt[k * 12 + 4];
#pragma unroll
    for (int e = 0; e < 8; ++e) {
      olo[e] = fmaf(hk[e], wl, olo[e]);
      ohi[e] = fmaf(hk[e], wh, ohi[e]);
    }
  }
#pragma unroll
  for (int e = 0; e < 8; ++e) {
    const int n = nb + e;
    if (n < NN) {
      x_out[n * HIDC + lane]      = olo[e];
      x_out[n * HIDC + 64 + lane] = ohi[e];
    }
  }
#pragma unroll
  for (int e = 0; e < 8; ++e) {
    const int n = nb + e;
    if (n < NN && lane < 3) {
      const float dg = fmaxf((float)(row_ptr[n + 1] - row_ptr[n]), 1.f);
      pos_out[n * 3 + lane] = pos_in[n * 3 + lane] + cu[n * 3 + lane] / dg;
    }
  }
  {
    f32x4 t0 = {olo[0], olo[1], olo[2], olo[3]};
    f32x4 t1 = {olo[4], olo[5], olo[6], olo[7]};
    *(f32x4*)&xt[lane * 12]     = t0;
    *(f32x4*)&xt[lane * 12 + 4] = t1;
    f32x4 t2 = {ohi[0], ohi[1], ohi[2], ohi[3]};
    f32x4 t3 = {ohi[4], ohi[5], ohi[6], ohi[7]};
    *(f32x4*)&xt[(64 + lane) * 12]     = t2;
    *(f32x4*)&xt[(64 + lane) * 12 + 4] = t3;
  }
  float a1[8], a2[8];
#pragma unroll
  for (int e = 0; e < 8; ++e) { a1[e] = 0.f; a2[e] = 0.f; }
#pragma unroll 4
  for (int k = 0; k < 128; ++k) {
    const float wa = Wn[k * 64 + lane];
    const float wb2 = Wn[(128 + k) * 64 + lane];
    float xk[8];
    *(f32x4*)&xk[0] = *(const f32x4*)&xt[k * 12];
    *(f32x4*)&xk[4] = *(const f32x4*)&xt[k * 12 + 4];
#pragma unroll
    for (int e = 0; e < 8; ++e) {
      a1[e] = fmaf(xk[e], wa, a1[e]);
      a2[e] = fmaf(xk[e], wb2, a2[e]);
    }
  }
#pragma unroll
  for (int e = 0; e < 8; ++e) {
    const int n = nb + e;
    if (n < NN) {
      P1[n * 64 + lane]  = a1[e];
      P2h[n * 64 + lane] = f2bf_rne(a2[e]);
    }
  }
}

// ------- K3b: layer-1 node MLP + fused batch mean-pool partials ----------------
__global__ __launch_bounds__(256) void k_node_l1(
    const float* __restrict__ x_in, const float* __restrict__ e_agg,
    const float* __restrict__ nw1, const float* __restrict__ nb1,
    const float* __restrict__ nw2, const float* __restrict__ nb2,
    const int* __restrict__ batch,
    float* __restrict__ g_sum, float* __restrict__ g_cnt) {
  __shared__ __align__(16) float xT[4][192 * 12];
  const int w = threadIdx.x >> 6, lane = threadIdx.x & 63;
  float* xt = xT[w];
  const int nb = (blockIdx.x * 4 + w) * 8;
#pragma unroll
  for (int e = 0; e < 8; ++e) {
    const int n = nb + e;
    const bool v = n < NN;
    xt[lane * 12 + e]         = v ? x_in[n * HIDC + lane] : 0.f;
    xt[(64 + lane) * 12 + e]  = v ? x_in[n * HIDC + 64 + lane] : 0.f;
    xt[(128 + lane) * 12 + e] = v ? e_agg[n * 64 + lane] : 0.f;
  }
  __syncthreads();
  float a[8];
#pragma unroll
  for (int e = 0; e < 8; ++e) a[e] = nb1[lane];
#pragma unroll 2
  for (int k = 0; k < 192; ++k) {
    const float wv = nw1[k * 64 + lane];
    float xk[8];
    *(f32x4*)&xk[0] = *(const f32x4*)&xt[k * 12];
    *(f32x4*)&xk[4] = *(const f32x4*)&xt[k * 12 + 4];
#pragma unroll
    for (int e = 0; e < 8; ++e) a[e] = fmaf(xk[e], wv, a[e]);
  }
#pragma unroll
  for (int e = 0; e < 8; ++e) a[e] = silu_f(a[e]);
  {
    f32x4 t0 = {a[0], a[1], a[2], a[3]};
    f32x4 t1 = {a[4], a[5], a[6], a[7]};
    *(f32x4*)&xt[lane * 12]     = t0;
    *(f32x4*)&xt[lane * 12 + 4] = t1;
  }
  float olo[8], ohi[8];
#pragma unroll
  for (int e = 0; e < 8; ++e) { olo[e] = nb2[lane]; ohi[e] = nb2[64 + lane]; }
#pragma unroll 2
  for (int k = 0; k < 64; ++k) {
    const float wl = nw2[k * HIDC + lane];
    const float wh = nw2[k * HIDC + 64 + lane];
    float hk[8];
    *(f32x4*)&hk[0] = *(const f32x4*)&xt[k * 12];
    *(f32x4*)&hk[4] = *(const f32x4*)&xt[k * 12 + 4];
#pragma unroll
    for (int e = 0; e < 8; ++e) {
      olo[e] = fmaf(hk[e], wl, olo[e]);
      ohi[e] = fmaf(hk[e], wh, ohi[e]);
    }
  }
  int curb = -1;
  float accL = 0.f, accH = 0.f, c = 0.f;
#pragma unroll
  for (int e = 0; e < 8; ++e) {
    const int n = nb + e;
    if (n < NN) {
      const int bg = batch[n];
      if (bg != curb) {
        if (curb >= 0) {
          atomicAdd(&g_sum[curb * HIDC + lane], accL);
          atomicAdd(&g_sum[curb * HIDC + 64 + lane], accH);
          if (lane == 0) atomicAdd(&g_cnt[curb], c);
        }
        curb = bg; accL = olo[e]; accH = ohi[e]; c = 1.f;
      } else {
        accL += olo[e]; accH += ohi[e]; c += 1.f;
      }
    }
  }
  if (curb >= 0) {
    atomicAdd(&g_sum[curb * HIDC + lane], accL);
    atomicAdd(&g_sum[curb * HIDC + 64 + lane], accH);
    if (lane == 0) atomicAdd(&g_cnt[curb], c);
  }
}

// ---------------- K5: relu(mean) -> relu(@w1+b1) -> @w2+b2 ----------------
__global__ __launch_bounds__(128) void k_final(
    const float* __restrict__ g_sum, const float* __restrict__ g_cnt,
    const float* __restrict__ w1, const float* __restrict__ b1,
    const float* __restrict__ w2, const float* __restrict__ b2,
    float* __restrict__ out) {
  __shared__ float sg[128];
  __shared__ float sh[128];
  const int g = blockIdx.x, j = threadIdx.x;
  const float c = fmaxf(g_cnt[g], 1.f);
  sg[j] = fmaxf(g_sum[g * HIDC + j] / c, 0.f);
  __syncthreads();
  float a = b1[j];
  for (int k = 0; k < 128; ++k) a += sg[k] * w1[k * 128 + j];
  sh[j] = fmaxf(a, 0.f);
  __syncthreads();
  if (j < OUTC) {
    float o = b2[j];
    for (int k = 0; k < 128; ++k) o += sh[k] * w2[k * OUTC + j];
    out[g * OUTC + j] = o;
  }
}

extern "C" void kernel_launch(void* const* d_in, const int* in_sizes, int n_in,
                              void* d_out, int out_size, void* d_ws, size_t ws_size,
                              hipStream_t stream) {
  const float* x     = (const float*)d_in[0];
  const float* pos   = (const float*)d_in[1];
  const float* eattr = (const float*)d_in[2];
  const int*   ei    = (const int*)d_in[3];
  const int*   batch = (const int*)d_in[4];
  const float* mlp_w[2]   = {(const float*)d_in[5],  (const float*)d_in[14]};
  const float* edge_w[2]  = {(const float*)d_in[6],  (const float*)d_in[15]};
  const float* edge_b[2]  = {(const float*)d_in[7],  (const float*)d_in[16]};
  const float* coord_w[2] = {(const float*)d_in[8],  (const float*)d_in[17]};
  const float* coord_b[2] = {(const float*)d_in[9],  (const float*)d_in[18]};
  const float* nw1[2]     = {(const float*)d_in[10], (const float*)d_in[19]};
  const float* nb1[2]     = {(const float*)d_in[11], (const float*)d_in[20]};
  const float* nw2[2]     = {(const float*)d_in[12], (const float*)d_in[21]};
  const float* nb2[2]     = {(const float*)d_in[13], (const float*)d_in[22]};
  const float* ow1 = (const float*)d_in[23];
  const float* ob1 = (const float*)d_in[24];
  const float* ow2 = (const float*)d_in[25];
  const float* ob2 = (const float*)d_in[26];
  float* out = (float*)d_out;

  char* p = (char*)d_ws;
  auto alloc = [&](size_t bytes) {
    void* r = (void*)p;
    p += (bytes + 255) & ~(size_t)255;
    return r;
  };
  float* P1            = (float*)alloc((size_t)NN * 64 * 4);
  unsigned short* P2h  = (unsigned short*)alloc((size_t)NN * 64 * 2);
  // ---- contiguous zero-region (single memset) ----
  char* zero_base      = p;
  float* e_agg         = (float*)alloc((size_t)NN * 64 * 4);
  float* cu            = (float*)alloc((size_t)NN * 3 * 4);
  float* g_sum         = (float*)alloc((size_t)GG * HIDC * 4);
  float* g_cnt         = (float*)alloc((size_t)GG * 4);
  int* cnt             = (int*)alloc((size_t)NN * 4);
  const size_t zero_sz = (size_t)(p - zero_base);
  // ---- non-zeroed scratch ----
  int* row_ptr         = (int*)alloc((size_t)(NN + 1) * 4);
  int* nxt             = (int*)alloc((size_t)NN * 4);
  int* sdst            = (int*)alloc((size_t)EE * 4);
  int* ssrc            = (int*)alloc((size_t)EE * 4);
  int* seid            = (int*)alloc((size_t)EE * 4);
  float* seattr        = (float*)alloc((size_t)EE * DD * 4);
  float* x1            = (float*)alloc((size_t)NN * HIDC * 4);
  float* pos1          = (float*)alloc((size_t)NN * 3 * 4);

  const int edgeBlocks = 1024;  // 4096 waves x (7|6) groups x 16 = 400000 exact

  (void)hipMemsetAsync(zero_base, 0, zero_sz, stream);

  // ---- sort chain + layer-0 precompute (fused into scatter dispatch) ----
  k_hist<<<SCATBLK, 256, 0, stream>>>(ei, cnt);
  k_scan<<<1, 1024, 0, stream>>>(cnt, row_ptr, nxt);
  k_sp<<<NODEBLK + SCATBLK, 256, 0, stream>>>(ei, nxt, sdst, ssrc, seid,
      x, mlp_w[0], P1, P2h);

  // ---- layer 0 (GATHER: reads eattr via seid, emits sorted seattr) ----
  k_edge<true, true><<<edgeBlocks, 256, 0, stream>>>(P1, P2h, pos, eattr,
      seattr, seid, sdst, ssrc, mlp_w[0], edge_w[0], edge_b[0],
      coord_w[0], coord_b[0], e_agg, cu);
  k_node_l0<<<NODEBLK, 256, 0, stream>>>(x, e_agg, nw1[0], nb1[0],
      nw2[0], nb2[0], pos, cu, row_ptr, x1, pos1, mlp_w[1], P1, P2h);

  // ---- layer 1 (reads sorted seattr sequentially) ----
  k_edge<false, false><<<edgeBlocks, 256, 0, stream>>>(P1, P2h, pos1, eattr,
      seattr, seid, sdst, ssrc, mlp_w[1], edge_w[1], edge_b[1],
      coord_w[1], coord_b[1], e_agg, cu);
  k_node_l1<<<NODEBLK, 256, 0, stream>>>(x1, e_agg, nw1[1], nb1[1],
      nw2[1], nb2[1], batch, g_sum, g_cnt);

  // ---- head ----
  k_final<<<GG, 128, 0, stream>>>(g_sum, g_cnt, ow1, ob1, ow2, ob2, out);
}

// Round 12
// 471.828 us; speedup vs baseline: 1.4223x; 1.0765x over previous
//
#include <hip/hip_runtime.h>
#include <math.h>

#define NN 25000
#define EE 400000
#define FF 128
#define DD 16
#define HH 64
#define HIDC 128
#define OUTC 32
#define GG 64
#define NODEBLK 782     // ceil(25000/32)  (k_sp precompute part)
#define SCATBLK 1563    // ceil(400000/256)
#define NTILES 1563     // ceil(25000/16)  (MFMA node tiles)

typedef __attribute__((ext_vector_type(8))) short short8;
typedef __attribute__((ext_vector_type(8))) unsigned short u16x8;
typedef __attribute__((ext_vector_type(4))) float f32x4;

union S8 { short8 v; unsigned short u[8]; };
union U8 { u16x8 v; unsigned short u[8]; };

__device__ __forceinline__ float silu_f(float v) {
    return v / (1.f + __expf(-v));
}

__device__ __forceinline__ unsigned short f2bf_rne(float f) {
  unsigned u = __float_as_uint(f);
  unsigned r = u + 0x7fffu + ((u >> 16) & 1u);
  return (unsigned short)(r >> 16);
}
__device__ __forceinline__ float bfbits2f(unsigned short b) {
  return __uint_as_float(((unsigned)b) << 16);
}

__device__ __forceinline__ void split8(const float* hv, S8& hi, S8& lo) {
#pragma unroll
  for (int j = 0; j < 8; ++j) {
    const unsigned short hb = (unsigned short)(__float_as_uint(hv[j]) >> 16);
    hi.u[j] = hb;
    lo.u[j] = f2bf_rne(hv[j] - bfbits2f(hb));
  }
}

// B[k=q*8+j][n=nc*16+m] fragment from row-major W (ldw = N), split hi/lo
__device__ __forceinline__ void loadBsplit(const float* __restrict__ W, int ldw,
                                           int k0, int n0, int q, int m,
                                           S8& bh, S8& bl) {
#pragma unroll
  for (int j = 0; j < 8; ++j) {
    const float wv = W[(size_t)(k0 + q * 8 + j) * ldw + n0 + m];
    const unsigned short hb = (unsigned short)(__float_as_uint(wv) >> 16);
    bh.u[j] = hb;
    bl.u[j] = f2bf_rne(wv - bfbits2f(hb));
  }
}

// 3-term split product: err ~2^-16 (near-fp32)
__device__ __forceinline__ f32x4 mfma3(const S8& ah, const S8& al,
                                       const S8& bh, const S8& bl, f32x4 c) {
  c = __builtin_amdgcn_mfma_f32_16x16x32_bf16(ah.v, bh.v, c, 0, 0, 0);
  c = __builtin_amdgcn_mfma_f32_16x16x32_bf16(al.v, bh.v, c, 0, 0, 0);
  c = __builtin_amdgcn_mfma_f32_16x16x32_bf16(ah.v, bl.v, c, 0, 0, 0);
  return c;
}

// ---------------- Sort step 1: histogram of dst ----------------
__global__ __launch_bounds__(256) void k_hist(
    const int* __restrict__ ei, int* __restrict__ cnt) {
  const int t = blockIdx.x * 256 + threadIdx.x;
  if (t < EE) atomicAdd(&cnt[ei[EE + t]], 1);
}

// ---------------- Sort step 2: exclusive scan ----------------
__global__ __launch_bounds__(1024) void k_scan(
    const int* __restrict__ cnt, int* __restrict__ row_ptr, int* __restrict__ next) {
  __shared__ int s[1024];
  const int t = threadIdx.x;
  const int base = t * 25;
  int loc[25];
  int sum = 0;
#pragma unroll
  for (int i = 0; i < 25; ++i) {
    const int n = base + i;
    loc[i] = (n < NN) ? cnt[n] : 0;
    sum += loc[i];
  }
  s[t] = sum;
  __syncthreads();
  for (int off = 1; off < 1024; off <<= 1) {
    const int v = (t >= off) ? s[t - off] : 0;
    __syncthreads();
    s[t] += v;
    __syncthreads();
  }
  int run = s[t] - sum;
#pragma unroll
  for (int i = 0; i < 25; ++i) {
    const int n = base + i;
    if (n < NN) {
      row_ptr[n] = run;
      next[n] = run;
      run += loc[i];
    }
  }
  if (t == 0) row_ptr[NN] = EE;
}

// ------- Fused: scatter (index-only) + layer-0 P precompute --------------------
__global__ __launch_bounds__(256) void k_sp(
    const int* __restrict__ ei, int* __restrict__ next,
    int* __restrict__ sdst, int* __restrict__ ssrc, int* __restrict__ seid,
    const float* __restrict__ X, const float* __restrict__ W,
    float* __restrict__ P1, unsigned short* __restrict__ P2h) {
  __shared__ __align__(16) float xT[4][128 * 12];
  if (blockIdx.x >= NODEBLK) {
    const int t = (blockIdx.x - NODEBLK) * 256 + threadIdx.x;
    if (t < EE) {
      const int d = ei[EE + t];
      const int slot = atomicAdd(&next[d], 1);
      sdst[slot] = d;
      ssrc[slot] = ei[t];
      seid[slot] = t;
    }
    return;
  }
  const int w = threadIdx.x >> 6, lane = threadIdx.x & 63;
  float* xt = xT[w];
  const int nb = (blockIdx.x * 4 + w) * 8;
#pragma unroll
  for (int e = 0; e < 8; ++e) {
    const int n = nb + e;
    const bool v = n < NN;
    xt[lane * 12 + e]        = v ? X[n * FF + lane] : 0.f;
    xt[(lane + 64) * 12 + e] = v ? X[n * FF + 64 + lane] : 0.f;
  }
  __syncthreads();
  float a1[8], a2[8];
#pragma unroll
  for (int e = 0; e < 8; ++e) { a1[e] = 0.f; a2[e] = 0.f; }
#pragma unroll 4
  for (int k = 0; k < 128; ++k) {
    const float wa = W[k * 64 + lane];
    const float wb = W[(128 + k) * 64 + lane];
    float xk[8];
    *(f32x4*)&xk[0] = *(const f32x4*)&xt[k * 12];
    *(f32x4*)&xk[4] = *(const f32x4*)&xt[k * 12 + 4];
#pragma unroll
    for (int e = 0; e < 8; ++e) {
      a1[e] = fmaf(xk[e], wa, a1[e]);
      a2[e] = fmaf(xk[e], wb, a2[e]);
    }
  }
#pragma unroll
  for (int e = 0; e < 8; ++e) {
    const int n = nb + e;
    if (n < NN) {
      P1[n * 64 + lane]  = a1[e];
      P2h[n * 64 + lane] = f2bf_rne(a2[e]);
    }
  }
}

// ---------------- K2: per-edge MLP via MFMA, dst-sorted (R10 config) -----------
// GATHER (l0): eattr loaded via seid, quantized once, stored to seattr_h (bf16,
// sequential); l1 reads seattr_h sequentially (half the bytes, no conversions).
template <bool COORD, bool GATHER>
__global__ __launch_bounds__(256, 4) void k_edge(
    const float* __restrict__ P1, const unsigned short* __restrict__ P2h,
    const float* __restrict__ pos, const float* __restrict__ eattr,
    unsigned short* __restrict__ seattr_h, const int* __restrict__ seid,
    const int* __restrict__ sdst, const int* __restrict__ ssrc,
    const float* __restrict__ mlp_w,
    const float* __restrict__ edge_w, const float* __restrict__ edge_b,
    const float* __restrict__ coord_w, const float* __restrict__ coord_b,
    float* __restrict__ e_agg, float* __restrict__ cu) {
  __shared__ __align__(16) float s_hs[4][16 * 76];
  __shared__ float s_diff[4][48];
  __shared__ float s_rad[4][16];
  __shared__ float s_red[4][16];
  const int tid = threadIdx.x, w = tid >> 6, lane = tid & 63;
  const int q = lane >> 4, m = lane & 15;

  S8 wB[2][4];
#pragma unroll
  for (int kc = 0; kc < 2; ++kc)
#pragma unroll
    for (int nc = 0; nc < 4; ++nc)
#pragma unroll
      for (int j = 0; j < 8; ++j)
        wB[kc][nc].u[j] = f2bf_rne(edge_w[(kc * 32 + q * 8 + j) * 64 + nc * 16 + m]);
  S8 w3B[4];
#pragma unroll
  for (int nc = 0; nc < 4; ++nc)
#pragma unroll
    for (int j = 0; j < 8; ++j)
      w3B[nc].u[j] = (lane < 32) ? f2bf_rne(mlp_w[256 * 64 + (q * 8 + j) * 64 + nc * 16 + m])
                                 : (unsigned short)0;
  float w4r[4], cwr[4], ebr[4];
#pragma unroll
  for (int nc = 0; nc < 4; ++nc) {
    w4r[nc] = mlp_w[272 * 64 + nc * 16 + m];
    ebr[nc] = edge_b[nc * 16 + m];
    cwr[nc] = COORD ? coord_w[nc * 16 + m] : 0.f;
  }
  const float cb = COORD ? coord_b[0] : 0.f;

  const int wave_id = blockIdx.x * 4 + w;               // 0..4095
  const int g0 = wave_id * 6 + (wave_id < 424 ? wave_id : 424);
  const int ng = (wave_id < 424) ? 7 : 6;

  const int pe = (lane < 48) ? (lane / 3) : 0;
  const int pc = lane - (lane / 3) * 3;

  int cur_dst = -1;
  float accum = 0.f;

  for (int g = 0; g < ng; ++g) {
    const int eb = (g0 + g) * 16;
    const int dm = sdst[eb + m];
    const int sm = ssrc[eb + m];
    f32x4 p1a[2], p1b[2];
    U8 p2r[2];
#pragma unroll
    for (int kc = 0; kc < 2; ++kc) {
      const float* pp1 = P1 + (size_t)dm * 64 + kc * 32 + q * 8;
      p1a[kc] = *(const f32x4*)pp1;
      p1b[kc] = *(const f32x4*)(pp1 + 4);
      p2r[kc].v = *(const u16x8*)(P2h + (size_t)sm * 64 + kc * 32 + q * 8);
    }
    if (lane < 48) {
      const int de = __shfl(dm, pe, 64), se = __shfl(sm, pe, 64);
      s_diff[w][lane] = pos[de * 3 + pc] - pos[se * 3 + pc];
    }
    S8 eaA;
#pragma unroll
    for (int j = 0; j < 8; ++j) eaA.u[j] = 0;
    if (lane < 32) {
      if (GATHER) {
        const int eid = seid[eb + m];
        const float* ep = &eattr[(size_t)eid * DD + q * 8];
        const f32x4 ea0 = *(const f32x4*)ep;
        const f32x4 ea1 = *(const f32x4*)(ep + 4);
#pragma unroll
        for (int j = 0; j < 4; ++j) {
          eaA.u[j]     = f2bf_rne(ea0[j]);
          eaA.u[4 + j] = f2bf_rne(ea1[j]);
        }
        *(short8*)&seattr_h[(size_t)(eb + m) * DD + q * 8] = eaA.v;
      } else {
        eaA.v = *(const short8*)&seattr_h[(size_t)(eb + m) * DD + q * 8];
      }
    }
    if (lane < 16) {
      const float d0 = s_diff[w][lane * 3 + 0];
      const float d1 = s_diff[w][lane * 3 + 1];
      const float d2 = s_diff[w][lane * 3 + 2];
      s_rad[w][lane] = fmaf(d0, d0, fmaf(d1, d1, d2 * d2));
    }
    float radr[4];
#pragma unroll
    for (int r = 0; r < 4; ++r) radr[r] = s_rad[w][q * 4 + r];
    f32x4 c3[4];
#pragma unroll
    for (int nc = 0; nc < 4; ++nc) {
      f32x4 z = {0.f, 0.f, 0.f, 0.f};
      c3[nc] = __builtin_amdgcn_mfma_f32_16x16x32_bf16(eaA.v, w3B[nc].v, z, 0, 0, 0);
    }
#pragma unroll
    for (int nc = 0; nc < 4; ++nc)
#pragma unroll
      for (int r = 0; r < 4; ++r)
        s_hs[w][(q * 4 + r) * 76 + nc * 16 + m] = fmaf(radr[r], w4r[nc], c3[nc][r]);
    S8 ahi[2], alo[2];
#pragma unroll
    for (int kc = 0; kc < 2; ++kc) {
      const float* hp = &s_hs[w][m * 76 + kc * 32 + q * 8];
      f32x4 h0 = *(const f32x4*)hp;
      f32x4 h1 = *(const f32x4*)(hp + 4);
      h0 = h0 + p1a[kc];
      h1 = h1 + p1b[kc];
      float hv[8];
      *(f32x4*)&hv[0] = h0;
      *(f32x4*)&hv[4] = h1;
#pragma unroll
      for (int j = 0; j < 8; ++j) {
        const float h = silu_f(hv[j] + bfbits2f(p2r[kc].u[j]));
        const unsigned short hb = (unsigned short)(__float_as_uint(h) >> 16);
        ahi[kc].u[j] = hb;
        alo[kc].u[j] = f2bf_rne(h - bfbits2f(hb));
      }
    }
    f32x4 o[4];
#pragma unroll
    for (int nc = 0; nc < 4; ++nc) {
      f32x4 bi = {ebr[nc], ebr[nc], ebr[nc], ebr[nc]};
      o[nc] = bi;
    }
#pragma unroll
    for (int kc = 0; kc < 2; ++kc)
#pragma unroll
      for (int nc = 0; nc < 4; ++nc) {
        o[nc] = __builtin_amdgcn_mfma_f32_16x16x32_bf16(ahi[kc].v, wB[kc][nc].v, o[nc], 0, 0, 0);
        o[nc] = __builtin_amdgcn_mfma_f32_16x16x32_bf16(alo[kc].v, wB[kc][nc].v, o[nc], 0, 0, 0);
      }
#pragma unroll
    for (int nc = 0; nc < 4; ++nc)
#pragma unroll
      for (int r = 0; r < 4; ++r) o[nc][r] = silu_f(o[nc][r]);
    if (COORD) {
#pragma unroll
      for (int r = 0; r < 4; ++r) {
        float v = o[0][r] * cwr[0] + o[1][r] * cwr[1] + o[2][r] * cwr[2] + o[3][r] * cwr[3];
        v += __shfl_xor(v, 1, 64);
        v += __shfl_xor(v, 2, 64);
        v += __shfl_xor(v, 4, 64);
        v += __shfl_xor(v, 8, 64);
        if (m == 0) s_red[w][q * 4 + r] = v;
      }
    }
#pragma unroll
    for (int nc = 0; nc < 4; ++nc)
#pragma unroll
      for (int r = 0; r < 4; ++r)
        s_hs[w][(q * 4 + r) * 76 + nc * 16 + m] = o[nc][r];
    for (int e = 0; e < 16; ++e) {
      const int dv = __shfl(dm, e, 64);
      const float v = s_hs[w][e * 76 + lane];
      if (dv == cur_dst) {
        accum += v;
      } else {
        if (cur_dst >= 0) atomicAdd(&e_agg[(size_t)cur_dst * 64 + lane], accum);
        cur_dst = dv;
        accum = v;
      }
    }
    if (COORD) {
      if (lane < 48) {
        const float s = silu_f(s_red[w][pe] + cb);
        atomicAdd(&cu[(size_t)__shfl(dm, pe, 64) * 3 + pc], s_diff[w][lane] * s);
      }
    }
  }
  if (cur_dst >= 0) atomicAdd(&e_agg[(size_t)cur_dst * 64 + lane], accum);
}

// ------- K3: node MLP via MFMA (3-term split, near-fp32). One 16-node tile/wave.
// L0: + pos update + e_agg rezero + layer-1 P precompute.
// L1: + fused batch mean-pool partials.
template <bool L0>
__global__ __launch_bounds__(256) void k_node(
    const float* __restrict__ x_in, float* __restrict__ e_agg,
    const float* __restrict__ nw1, const float* __restrict__ nb1,
    const float* __restrict__ nw2, const float* __restrict__ nb2,
    const float* __restrict__ pos_in, const float* __restrict__ cu,
    const int* __restrict__ row_ptr,
    float* __restrict__ x_out, float* __restrict__ pos_out,
    const float* __restrict__ Wn, float* __restrict__ P1,
    unsigned short* __restrict__ P2h,
    const int* __restrict__ batch,
    float* __restrict__ g_sum, float* __restrict__ g_cnt) {
  __shared__ __align__(16) float sbuf[4][16 * 132];   // stride 132: 2-way banks (free)
  const int tid = threadIdx.x, w = tid >> 6, lane = tid & 63;
  const int q = lane >> 4, m = lane & 15;
  const int tile = blockIdx.x * 4 + w;
  if (tile >= NTILES) return;
  const int n0 = tile * 16;
  const int nm = n0 + m;
  const bool vm = nm < NN;
  float* sb = sbuf[w];

  // ---- stage 1: A = [x | e_agg] (K=192), split hi/lo ----
  S8 axh[6], axl[6];
#pragma unroll
  for (int kc = 0; kc < 6; ++kc) {
    float hv[8] = {0.f, 0.f, 0.f, 0.f, 0.f, 0.f, 0.f, 0.f};
    if (vm) {
      const float* src = (kc < 4) ? (x_in + (size_t)nm * HIDC + kc * 32 + q * 8)
                                  : (e_agg + (size_t)nm * 64 + (kc - 4) * 32 + q * 8);
      *(f32x4*)&hv[0] = *(const f32x4*)src;
      *(f32x4*)&hv[4] = *(const f32x4*)(src + 4);
    }
    split8(hv, axh[kc], axl[kc]);
  }
  if (L0 && vm) {   // pre-zero e_agg for layer 1 (each lane zeroes exactly what it read)
    const f32x4 z = {0.f, 0.f, 0.f, 0.f};
    float* ez = e_agg + (size_t)nm * 64 + q * 8;
    *(f32x4*)ez = z; *(f32x4*)(ez + 4) = z;
    *(f32x4*)(ez + 32) = z; *(f32x4*)(ez + 36) = z;
  }
  // ---- h1 = silu(A @ nw1 + nb1), N=64 ----
#pragma unroll
  for (int nc = 0; nc < 4; ++nc) {
    const float b = nb1[nc * 16 + m];
    f32x4 acc = {b, b, b, b};
#pragma unroll
    for (int kc = 0; kc < 6; ++kc) {
      S8 bh, bl;
      loadBsplit(nw1, 64, kc * 32, nc * 16, q, m, bh, bl);
      acc = mfma3(axh[kc], axl[kc], bh, bl, acc);
    }
#pragma unroll
    for (int r = 0; r < 4; ++r)
      sb[(q * 4 + r) * 132 + nc * 16 + m] = silu_f(acc[r]);
  }
  // ---- read h1 as A-fragments (same-wave DS ordering), split ----
  S8 ah[2], al[2];
#pragma unroll
  for (int kc = 0; kc < 2; ++kc) {
    float hv[8];
    const float* hp = &sb[m * 132 + kc * 32 + q * 8];
    *(f32x4*)&hv[0] = *(const f32x4*)hp;
    *(f32x4*)&hv[4] = *(const f32x4*)(hp + 4);
    split8(hv, ah[kc], al[kc]);
  }
  // ---- h2 = h1 @ nw2 + nb2, N=128 ----
  f32x4 hh[8];
#pragma unroll
  for (int nc = 0; nc < 8; ++nc) {
    const float b = nb2[nc * 16 + m];
    f32x4 acc = {b, b, b, b};
#pragma unroll
    for (int kc = 0; kc < 2; ++kc) {
      S8 bh, bl;
      loadBsplit(nw2, 128, kc * 32, nc * 16, q, m, bh, bl);
      acc = mfma3(ah[kc], al[kc], bh, bl, acc);
    }
    hh[nc] = acc;
  }
  if (L0) {
    // store x1 + stage to LDS for the P precompute transpose
#pragma unroll
    for (int nc = 0; nc < 8; ++nc)
#pragma unroll
      for (int r = 0; r < 4; ++r) {
        const int n = n0 + q * 4 + r;
        sb[(q * 4 + r) * 132 + nc * 16 + m] = hh[nc][r];
        if (n < NN) x_out[(size_t)n * HIDC + nc * 16 + m] = hh[nc][r];
      }
    // pos update (16 nodes x 3 comps on lanes 0..47)
    if (lane < 48) {
      const int pe2 = lane / 3, pc2 = lane - pe2 * 3;
      const int n = n0 + pe2;
      if (n < NN) {
        const float dg = fmaxf((float)(row_ptr[n + 1] - row_ptr[n]), 1.f);
        pos_out[n * 3 + pc2] = pos_in[n * 3 + pc2] + cu[n * 3 + pc2] / dg;
      }
    }
    // ---- P = x1 @ Wn (rows 0..127 -> P1 fp32, 128..255 -> P2 bf16) ----
    S8 a1h[4], a1l[4];
#pragma unroll
    for (int kc = 0; kc < 4; ++kc) {
      float hv[8];
      const float* hp = &sb[m * 132 + kc * 32 + q * 8];
      *(f32x4*)&hv[0] = *(const f32x4*)hp;
      *(f32x4*)&hv[4] = *(const f32x4*)(hp + 4);
      split8(hv, a1h[kc], a1l[kc]);
    }
#pragma unroll
    for (int nc = 0; nc < 8; ++nc) {
      const float* Wb = Wn + (size_t)(nc < 4 ? 0 : 128 * 64);
      const int ncc = nc & 3;
      f32x4 acc = {0.f, 0.f, 0.f, 0.f};
#pragma unroll
      for (int kc = 0; kc < 4; ++kc) {
        S8 bh, bl;
        loadBsplit(Wb, 64, kc * 32, ncc * 16, q, m, bh, bl);
        acc = mfma3(a1h[kc], a1l[kc], bh, bl, acc);
      }
#pragma unroll
      for (int r = 0; r < 4; ++r) {
        const int n = n0 + q * 4 + r;
        if (n < NN) {
          if (nc < 4) P1[(size_t)n * 64 + ncc * 16 + m] = acc[r];
          else        P2h[(size_t)n * 64 + ncc * 16 + m] = f2bf_rne(acc[r]);
        }
      }
    }
  } else {
    // ---- fused mean-pool partials (batch sorted; run-compress per lane) ----
    int curb = -1;
    float cnt2 = 0.f;
    float pacc[8];
#pragma unroll
    for (int r = 0; r < 4; ++r) {
      const int n = n0 + q * 4 + r;
      if (n < NN) {
        const int bg = batch[n];
        if (bg != curb) {
          if (curb >= 0) {
#pragma unroll
            for (int nc = 0; nc < 8; ++nc)
              atomicAdd(&g_sum[curb * HIDC + nc * 16 + m], pacc[nc]);
            if (m == 0) atomicAdd(&g_cnt[curb], cnt2);
          }
          curb = bg;
#pragma unroll
          for (int nc = 0; nc < 8; ++nc) pacc[nc] = hh[nc][r];
          cnt2 = 1.f;
        } else {
#pragma unroll
          for (int nc = 0; nc < 8; ++nc) pacc[nc] += hh[nc][r];
          cnt2 += 1.f;
        }
      }
    }
    if (curb >= 0) {
#pragma unroll
      for (int nc = 0; nc < 8; ++nc)
        atomicAdd(&g_sum[curb * HIDC + nc * 16 + m], pacc[nc]);
      if (m == 0) atomicAdd(&g_cnt[curb], cnt2);
    }
  }
}

// ---------------- K5: relu(mean) -> relu(@w1+b1) -> @w2+b2 ----------------
__global__ __launch_bounds__(128) void k_final(
    const float* __restrict__ g_sum, const float* __restrict__ g_cnt,
    const float* __restrict__ w1, const float* __restrict__ b1,
    const float* __restrict__ w2, const float* __restrict__ b2,
    float* __restrict__ out) {
  __shared__ float sg[128];
  __shared__ float sh[128];
  const int g = blockIdx.x, j = threadIdx.x;
  const float c = fmaxf(g_cnt[g], 1.f);
  sg[j] = fmaxf(g_sum[g * HIDC + j] / c, 0.f);
  __syncthreads();
  float a = b1[j];
  for (int k = 0; k < 128; ++k) a += sg[k] * w1[k * 128 + j];
  sh[j] = fmaxf(a, 0.f);
  __syncthreads();
  if (j < OUTC) {
    float o = b2[j];
    for (int k = 0; k < 128; ++k) o += sh[k] * w2[k * OUTC + j];
    out[g * OUTC + j] = o;
  }
}

extern "C" void kernel_launch(void* const* d_in, const int* in_sizes, int n_in,
                              void* d_out, int out_size, void* d_ws, size_t ws_size,
                              hipStream_t stream) {
  const float* x     = (const float*)d_in[0];
  const float* pos   = (const float*)d_in[1];
  const float* eattr = (const float*)d_in[2];
  const int*   ei    = (const int*)d_in[3];
  const int*   batch = (const int*)d_in[4];
  const float* mlp_w[2]   = {(const float*)d_in[5],  (const float*)d_in[14]};
  const float* edge_w[2]  = {(const float*)d_in[6],  (const float*)d_in[15]};
  const float* edge_b[2]  = {(const float*)d_in[7],  (const float*)d_in[16]};
  const float* coord_w[2] = {(const float*)d_in[8],  (const float*)d_in[17]};
  const float* coord_b[2] = {(const float*)d_in[9],  (const float*)d_in[18]};
  const float* nw1[2]     = {(const float*)d_in[10], (const float*)d_in[19]};
  const float* nb1[2]     = {(const float*)d_in[11], (const float*)d_in[20]};
  const float* nw2[2]     = {(const float*)d_in[12], (const float*)d_in[21]};
  const float* nb2[2]     = {(const float*)d_in[13], (const float*)d_in[22]};
  const float* ow1 = (const float*)d_in[23];
  const float* ob1 = (const float*)d_in[24];
  const float* ow2 = (const float*)d_in[25];
  const float* ob2 = (const float*)d_in[26];
  float* out = (float*)d_out;

  char* p = (char*)d_ws;
  auto alloc = [&](size_t bytes) {
    void* r = (void*)p;
    p += (bytes + 255) & ~(size_t)255;
    return r;
  };
  float* P1            = (float*)alloc((size_t)NN * 64 * 4);
  unsigned short* P2h  = (unsigned short*)alloc((size_t)NN * 64 * 2);
  // ---- contiguous zero-region (single memset) ----
  char* zero_base      = p;
  float* e_agg         = (float*)alloc((size_t)NN * 64 * 4);
  float* cu            = (float*)alloc((size_t)NN * 3 * 4);
  float* g_sum         = (float*)alloc((size_t)GG * HIDC * 4);
  float* g_cnt         = (float*)alloc((size_t)GG * 4);
  int* cnt             = (int*)alloc((size_t)NN * 4);
  const size_t zero_sz = (size_t)(p - zero_base);
  // ---- non-zeroed scratch ----
  int* row_ptr         = (int*)alloc((size_t)(NN + 1) * 4);
  int* nxt             = (int*)alloc((size_t)NN * 4);
  int* sdst            = (int*)alloc((size_t)EE * 4);
  int* ssrc            = (int*)alloc((size_t)EE * 4);
  int* seid            = (int*)alloc((size_t)EE * 4);
  unsigned short* seah = (unsigned short*)alloc((size_t)EE * DD * 2);
  float* x1            = (float*)alloc((size_t)NN * HIDC * 4);
  float* pos1          = (float*)alloc((size_t)NN * 3 * 4);

  const int edgeBlocks = 1024;   // 4096 waves x (7|6) groups x 16 = 400000 exact
  const int nodeTileBlk = (NTILES + 3) / 4;  // 391

  (void)hipMemsetAsync(zero_base, 0, zero_sz, stream);

  // ---- sort chain + layer-0 precompute (fused into scatter dispatch) ----
  k_hist<<<SCATBLK, 256, 0, stream>>>(ei, cnt);
  k_scan<<<1, 1024, 0, stream>>>(cnt, row_ptr, nxt);
  k_sp<<<NODEBLK + SCATBLK, 256, 0, stream>>>(ei, nxt, sdst, ssrc, seid,
      x, mlp_w[0], P1, P2h);

  // ---- layer 0 ----
  k_edge<true, true><<<edgeBlocks, 256, 0, stream>>>(P1, P2h, pos, eattr,
      seah, seid, sdst, ssrc, mlp_w[0], edge_w[0], edge_b[0],
      coord_w[0], coord_b[0], e_agg, cu);
  k_node<true><<<nodeTileBlk, 256, 0, stream>>>(x, e_agg, nw1[0], nb1[0],
      nw2[0], nb2[0], pos, cu, row_ptr, x1, pos1, mlp_w[1], P1, P2h,
      batch, g_sum, g_cnt);

  // ---- layer 1 ----
  k_edge<false, false><<<edgeBlocks, 256, 0, stream>>>(P1, P2h, pos1, eattr,
      seah, seid, sdst, ssrc, mlp_w[1], edge_w[1], edge_b[1],
      coord_w[1], coord_b[1], e_agg, cu);
  k_node<false><<<nodeTileBlk, 256, 0, stream>>>(x1, e_agg, nw1[1], nb1[1],
      nw2[1], nb2[1], pos1, cu, row_ptr, x1, pos1, mlp_w[1], P1, P2h,
      batch, g_sum, g_cnt);

  // ---- head ----
  k_final<<<GG, 128, 0, stream>>>(g_sum, g_cnt, ow1, ob1, ow2, ob2, out);
}